// Round 1
// 537.676 us; speedup vs baseline: 1.0345x; 1.0345x over previous
//
#include <hip/hip_runtime.h>
#include <hip/hip_bf16.h>

#define N_NODES 20000
#define N_EDGES 100000
#define N_LAYERS 25
#define NPAD 20096   // 157*128
#define EPS_BN 1e-5f
#define LOG2E 1.44269504088896340736f
#define NL_NN (N_LAYERS * N_NODES)          // 500000
#define TOTAL_E (N_LAYERS * N_EDGES)        // 2500000
#define SCAN_BLKS ((NL_NN + 1023) / 1024)   // 489
#define QUARTER_N 5000
#define CNT_BLKS (N_LAYERS * 4)             // 100
#define XLR_BASE CNT_BLKS                   // 100
#define XLR_BLKS (NL_NN / 16)               // 31250
#define W1T_BASE (XLR_BASE + XLR_BLKS)      // 31350
#define PREP_BLKS (W1T_BASE + 700)          // 32050
#define EDGE_BLKS ((TOTAL_E + 1023) / 1024) // 2442
#define FILL_BLKS (EDGE_BLKS + SCAN_BLKS)
#define NGRP 14                             // 7 col-blocks x 2 wc halves
#define ATTN_BLKS (NL_NN / 4)               // 125000 = 8 * 15625
#define ATTN_PER_XCD (ATTN_BLKS / 8)        // 15625

typedef short short8 __attribute__((ext_vector_type(8)));
typedef short short4v __attribute__((ext_vector_type(4)));
typedef float floatx4 __attribute__((ext_vector_type(4)));
typedef int int8v __attribute__((ext_vector_type(8)));

template <int PAT>
__device__ __forceinline__ float swz(float v) {
  return __int_as_float(__builtin_amdgcn_ds_swizzle(__float_as_int(v), PAT));
}

template <int CTRL>
__device__ __forceinline__ float dpp_add(float v) {
  int r = __builtin_amdgcn_update_dpp(0, __float_as_int(v), CTRL, 0xF, 0xF, true);
  return v + __int_as_float(r);
}

// int index on purpose: 32-bit address math
__device__ __forceinline__ float ldbf(const unsigned short* __restrict__ p, int idx) {
  return __uint_as_float((unsigned)p[idx] << 16);
}

__device__ __forceinline__ unsigned short bfbits(float v) {
  return __builtin_bit_cast(unsigned short, (__hip_bfloat16)v);
}

// async global->LDS, 16B per lane; LDS dest = wave-uniform base + lane*16
__device__ __forceinline__ void gl_lds16(const short* g, short* l) {
  __builtin_amdgcn_global_load_lds(
      (const __attribute__((address_space(1))) void*)g,
      (__attribute__((address_space(3))) void*)l, 16, 0, 0);
}

// scalar load of 8 edge records (64B) + wait, single asm so the wait is
// inseparable from the loads (no rule-18 hoisting hazard)
__device__ __forceinline__ void sload8(const int2* p, int8v& ra, int8v& rb) {
  asm volatile(
      "s_load_dwordx8 %0, %2, 0x0\n\t"
      "s_load_dwordx8 %1, %2, 0x20\n\t"
      "s_waitcnt lgkmcnt(0)"
      : "=s"(ra), "=s"(rb)
      : "s"(p));
}

// 8-chain interleaved 16-lane reduce: single-instruction DPP adds.
// 8-way interleave gives 7-instr gaps (>=2 wait states VALU->DPP);
// s_nop 1 guards asm entry/exit adjacency.
__device__ __forceinline__ void red8(float& p0, float& p1, float& p2, float& p3,
                                     float& p4, float& p5, float& p6, float& p7) {
  asm volatile(
      "s_nop 1\n\t"
      "v_add_f32_dpp %0, %0, %0 quad_perm:[1,0,3,2] row_mask:0xf bank_mask:0xf\n\t"
      "v_add_f32_dpp %1, %1, %1 quad_perm:[1,0,3,2] row_mask:0xf bank_mask:0xf\n\t"
      "v_add_f32_dpp %2, %2, %2 quad_perm:[1,0,3,2] row_mask:0xf bank_mask:0xf\n\t"
      "v_add_f32_dpp %3, %3, %3 quad_perm:[1,0,3,2] row_mask:0xf bank_mask:0xf\n\t"
      "v_add_f32_dpp %4, %4, %4 quad_perm:[1,0,3,2] row_mask:0xf bank_mask:0xf\n\t"
      "v_add_f32_dpp %5, %5, %5 quad_perm:[1,0,3,2] row_mask:0xf bank_mask:0xf\n\t"
      "v_add_f32_dpp %6, %6, %6 quad_perm:[1,0,3,2] row_mask:0xf bank_mask:0xf\n\t"
      "v_add_f32_dpp %7, %7, %7 quad_perm:[1,0,3,2] row_mask:0xf bank_mask:0xf\n\t"
      "v_add_f32_dpp %0, %0, %0 quad_perm:[2,3,0,1] row_mask:0xf bank_mask:0xf\n\t"
      "v_add_f32_dpp %1, %1, %1 quad_perm:[2,3,0,1] row_mask:0xf bank_mask:0xf\n\t"
      "v_add_f32_dpp %2, %2, %2 quad_perm:[2,3,0,1] row_mask:0xf bank_mask:0xf\n\t"
      "v_add_f32_dpp %3, %3, %3 quad_perm:[2,3,0,1] row_mask:0xf bank_mask:0xf\n\t"
      "v_add_f32_dpp %4, %4, %4 quad_perm:[2,3,0,1] row_mask:0xf bank_mask:0xf\n\t"
      "v_add_f32_dpp %5, %5, %5 quad_perm:[2,3,0,1] row_mask:0xf bank_mask:0xf\n\t"
      "v_add_f32_dpp %6, %6, %6 quad_perm:[2,3,0,1] row_mask:0xf bank_mask:0xf\n\t"
      "v_add_f32_dpp %7, %7, %7 quad_perm:[2,3,0,1] row_mask:0xf bank_mask:0xf\n\t"
      "v_add_f32_dpp %0, %0, %0 row_half_mirror row_mask:0xf bank_mask:0xf\n\t"
      "v_add_f32_dpp %1, %1, %1 row_half_mirror row_mask:0xf bank_mask:0xf\n\t"
      "v_add_f32_dpp %2, %2, %2 row_half_mirror row_mask:0xf bank_mask:0xf\n\t"
      "v_add_f32_dpp %3, %3, %3 row_half_mirror row_mask:0xf bank_mask:0xf\n\t"
      "v_add_f32_dpp %4, %4, %4 row_half_mirror row_mask:0xf bank_mask:0xf\n\t"
      "v_add_f32_dpp %5, %5, %5 row_half_mirror row_mask:0xf bank_mask:0xf\n\t"
      "v_add_f32_dpp %6, %6, %6 row_half_mirror row_mask:0xf bank_mask:0xf\n\t"
      "v_add_f32_dpp %7, %7, %7 row_half_mirror row_mask:0xf bank_mask:0xf\n\t"
      "v_add_f32_dpp %0, %0, %0 row_mirror row_mask:0xf bank_mask:0xf\n\t"
      "v_add_f32_dpp %1, %1, %1 row_mirror row_mask:0xf bank_mask:0xf\n\t"
      "v_add_f32_dpp %2, %2, %2 row_mirror row_mask:0xf bank_mask:0xf\n\t"
      "v_add_f32_dpp %3, %3, %3 row_mirror row_mask:0xf bank_mask:0xf\n\t"
      "v_add_f32_dpp %4, %4, %4 row_mirror row_mask:0xf bank_mask:0xf\n\t"
      "v_add_f32_dpp %5, %5, %5 row_mirror row_mask:0xf bank_mask:0xf\n\t"
      "v_add_f32_dpp %6, %6, %6 row_mirror row_mask:0xf bank_mask:0xf\n\t"
      "v_add_f32_dpp %7, %7, %7 row_mirror row_mask:0xf bank_mask:0xf\n\t"
      "s_nop 1"
      : "+v"(p0), "+v"(p1), "+v"(p2), "+v"(p3),
        "+v"(p4), "+v"(p5), "+v"(p6), "+v"(p7));
}

// single-chain 16-lane reduce (self-loop), s_nop 1 padding for DPP hazards
__device__ __forceinline__ float red1(float p) {
  asm volatile(
      "s_nop 1\n\t"
      "v_add_f32_dpp %0, %0, %0 quad_perm:[1,0,3,2] row_mask:0xf bank_mask:0xf\n\t"
      "s_nop 1\n\t"
      "v_add_f32_dpp %0, %0, %0 quad_perm:[2,3,0,1] row_mask:0xf bank_mask:0xf\n\t"
      "s_nop 1\n\t"
      "v_add_f32_dpp %0, %0, %0 row_half_mirror row_mask:0xf bank_mask:0xf\n\t"
      "s_nop 1\n\t"
      "v_add_f32_dpp %0, %0, %0 row_mirror row_mask:0xf bank_mask:0xf\n\t"
      "s_nop 1"
      : "+v"(p));
  return p;
}

// --- prep: count (LDS histogram, captures per-edge rank) + xlr + w1t --------
__global__ __launch_bounds__(1024) void prep_kernel(
    const int* __restrict__ ei, const float* __restrict__ x,
    const float* __restrict__ Wl, const float* __restrict__ bl,
    const float* __restrict__ Wr, const float* __restrict__ br,
    const float* __restrict__ W1, int* __restrict__ cnt,
    int* __restrict__ rank,
    unsigned short* __restrict__ xlb, unsigned short* __restrict__ xrb,
    __hip_bfloat16* __restrict__ W1bT) {
  __shared__ int smem[QUARTER_N];  // 20 KB (count hist); w1t reuses as float tile
  int b = blockIdx.x;
  if (b < XLR_BASE) {
    int l = b >> 2, base = (b & 3) * QUARTER_N;
    for (int i = threadIdx.x; i < QUARTER_N; i += 1024) smem[i] = 0;
    __syncthreads();
    const int* dstp = ei + (size_t)l * 2 * N_EDGES + N_EDGES;
    int* rkp = rank + l * N_EDGES;
    for (int e = threadIdx.x; e < N_EDGES; e += 1024) {
      int d = dstp[e] - base;
      if ((unsigned)d < (unsigned)QUARTER_N) rkp[e] = atomicAdd(&smem[d], 1);
    }
    __syncthreads();
    int* outp = cnt + l * N_NODES + base;
    for (int i = threadIdx.x; i < QUARTER_N; i += 1024) outp[i] = smem[i];
  } else if (b < W1T_BASE) {
    int wid = (b - XLR_BASE) * 16 + (threadIdx.x >> 6);
    int lane = threadIdx.x & 63;
    int l = wid / N_NODES, n = wid - l * N_NODES;
    float a = bl[l * 64 + lane];
    float c = br[l * 64 + lane];
#pragma unroll
    for (int k = 0; k < 5; k++) {
      float xk = x[n * 5 + k];
      a = fmaf(xk, Wl[(l * 5 + k) * 64 + lane], a);
      c = fmaf(xk, Wr[(l * 5 + k) * 64 + lane], c);
    }
    xlb[wid * 64 + lane] = bfbits(a);
    xrb[wid * 64 + lane] = bfbits(c);
  } else {
    float* tile = (float*)smem;  // [32][33]
    int bb = b - W1T_BASE;
    int j0 = (bb % 28) * 32, k0 = (bb / 28) * 32;
    int tx = threadIdx.x & 31, ty = threadIdx.x >> 5;
    tile[ty * 33 + tx] = (j0 + tx < 800) ? W1[(k0 + ty) * 800 + j0 + tx] : 0.f;
    __syncthreads();
    W1bT[(size_t)(j0 + ty) * 800 + k0 + tx] = (__hip_bfloat16)tile[tx * 33 + ty];
  }
}

// -------- scan_a: per-block scan; also zero gsum/gsumsq ---------------------
__global__ __launch_bounds__(1024) void scan_a(const int* __restrict__ cnt,
                                               int* __restrict__ scn,
                                               int* __restrict__ btot,
                                               float* __restrict__ gsum,
                                               float* __restrict__ gsumsq) {
  int t = threadIdx.x, b = blockIdx.x;
  int i = b * 1024 + t;
  int lane = t & 63, wv = t >> 6;
  int v = (i < NL_NN) ? cnt[i] : 0;
  int sc = v;
#pragma unroll
  for (int off = 1; off < 64; off <<= 1) {
    int u = __shfl_up(sc, off);
    if (lane >= off) sc += u;
  }
  __shared__ int ws[16];
  if (lane == 63) ws[wv] = sc;
  __syncthreads();
  if (t < 16) {
    int xx = ws[t];
#pragma unroll
    for (int off = 1; off < 16; off <<= 1) {
      int u = __shfl_up(xx, off);
      if (t >= off) xx += u;
    }
    ws[t] = xx;
  }
  __syncthreads();
  int bofs = wv ? ws[wv - 1] : 0;
  if (i < NL_NN) scn[i] = bofs + sc - v;
  if (t == 0) btot[b] = ws[15];
  if (b == 200 && t < N_LAYERS * 32) {
    gsum[t] = 0.f;
    gsumsq[t] = 0.f;
  }
}

__global__ __launch_bounds__(512) void scan_b(const int* __restrict__ btot,
                                              int* __restrict__ boff) {
  int t = threadIdx.x;
  int lane = t & 63, wv = t >> 6;
  int v = (t < SCAN_BLKS) ? btot[t] : 0;
  int sc = v;
#pragma unroll
  for (int off = 1; off < 64; off <<= 1) {
    int u = __shfl_up(sc, off);
    if (lane >= off) sc += u;
  }
  __shared__ int ws[8];
  if (lane == 63) ws[wv] = sc;
  __syncthreads();
  if (t < 8) {
    int xx = ws[t];
#pragma unroll
    for (int off = 1; off < 8; off <<= 1) {
      int u = __shfl_up(xx, off);
      if (t >= off) xx += u;
    }
    ws[t] = xx;
  }
  __syncthreads();
  int bofs = wv ? ws[wv - 1] : 0;
  if (t < SCAN_BLKS) boff[t] = bofs + sc - v;
}

// ------- fill: edge-parallel, atomic-free (rank from prep); tail -> rowfin --
// also zero-pads 8 records past TOTAL_E so attn's 8-wide chunks can over-read
__global__ __launch_bounds__(1024) void fill_kernel(const int* __restrict__ ei,
                                                    const float* __restrict__ ew,
                                                    const int* __restrict__ scn,
                                                    const int* __restrict__ boff,
                                                    const int* __restrict__ rank,
                                                    int* __restrict__ rowfin,
                                                    int2* __restrict__ ep) {
  int b = blockIdx.x;
  if (b < EDGE_BLKS) {
    int idx = b * 1024 + threadIdx.x;
    if (idx >= TOTAL_E) return;
    int l = idx / N_EDGES, e = idx - l * N_EDGES;
    int src = ei[(size_t)l * 2 * N_EDGES + e];
    int dst = ei[(size_t)l * 2 * N_EDGES + N_EDGES + e];
    int g = l * N_NODES + dst;
    int pos = scn[g] + boff[g >> 10] + rank[idx];
    int2 rec;
    rec.x = src;
    rec.y = __float_as_int(ew[(size_t)l * N_EDGES + e]);
    ep[pos] = rec;
  } else {
    int i = (b - EDGE_BLKS) * 1024 + threadIdx.x;
    if (i < NL_NN) rowfin[i] = scn[i] + boff[i >> 10];
    if (i == 0) rowfin[NL_NN] = TOTAL_E;
    if (i < 8) {
      int2 z;
      z.x = 0;
      z.y = 0;
      ep[TOTAL_E + i] = z;
    }
  }
}

// ---------------- fused GAT layer: 1 wave per (layer,node) ------------------
// latency-oriented rewrite: scalar (SMEM) edge records, 8-deep branch-free
// gather/score chunks with -inf softmax-bias masking, XCD-swizzled blocks so
// each layer's 2.56MB xl slice stays XCD-L2-resident, fused DPP reduces.
__global__ __launch_bounds__(256) void attn_kernel(
    const unsigned short* __restrict__ xlg, const unsigned short* __restrict__ xrg,
    const int* __restrict__ rowfin, const int2* __restrict__ ep,
    const float* __restrict__ We, const float* __restrict__ att,
    const float* __restrict__ cbias, unsigned short* __restrict__ out_pre) {
  int b = blockIdx.x;
  int nb = (b & 7) * ATTN_PER_XCD + (b >> 3);  // bijective XCD-chunk swizzle
  int wid = nb * 4 + (threadIdx.x >> 6);
  int lane = threadIdx.x & 63;
  int l = wid / N_NODES, n = wid - l * N_NODES;

  const unsigned short* xlb = xlg + (size_t)l * N_NODES * 64;
  float wev = We[l * 64 + lane];
  float att2v = att[l * 64 + lane] * LOG2E;

  float xrn = ldbf(xrg, wid * 64 + lane);
  float xln = ldbf(xlb, n * 64 + lane);

  int start = __builtin_amdgcn_readfirstlane(rowfin[wid]);
  int end   = __builtin_amdgcn_readfirstlane(rowfin[wid + 1]);
  int cnt = end - start;

  float ssum = 0.f, acc = 0.f, ewsum = 0.f;
  int nchunk = (cnt + 7) >> 3;
  for (int c = 0; c < nchunk; c++) {
    const int2* pchunk = ep + start + c * 8;
    int8v ra, rb;
    sload8(pchunk, ra, rb);
    int m = cnt - c * 8;  // valid edges this chunk (>=1; >=8 if not final)
#define RECS(k) ((k) < 4 ? ra[2 * (k)] : rb[2 * ((k)-4)])
#define RECW(k) ((k) < 4 ? ra[2 * (k) + 1] : rb[2 * ((k)-4) + 1])
    float xa[8], pk[8], wv[8];
#pragma unroll
    for (int k = 0; k < 8; k++) {
      const unsigned short* ps = xlb + RECS(k) * 64;  // uniform base -> saddr
      xa[k] = ldbf(ps, lane);                         // all 8 gathers in flight
    }
#pragma unroll
    for (int k = 0; k < 8; k++) {
      bool ok = k < m;                         // wave-uniform -> s_cselect
      int wbits = ok ? RECW(k) : 0;
      wv[k] = __int_as_float(wbits);
      int bbits = ok ? 0 : (int)0xff800000;    // -inf bias => exp2 -> 0
      float bias = __int_as_float(bbits);
      float v = xa[k] + fmaf(wv[k], wev, xrn);
      float lk = fmaxf(v, 0.2f * v);
      pk[k] = fmaf(lk, att2v, bias);
    }
#undef RECS
#undef RECW
    red8(pk[0], pk[1], pk[2], pk[3], pk[4], pk[5], pk[6], pk[7]);
#pragma unroll
    for (int k = 0; k < 8; k++) pk[k] += swz<0x401F>(pk[k]);
#pragma unroll
    for (int k = 0; k < 8; k++) {
      float pe = __builtin_amdgcn_exp2f(pk[k]);
      ssum += pe;
      acc = fmaf(xa[k], pe, acc);
      ewsum += wv[k];
    }
  }
  // self-loop edge with mean incoming weight
  {
    float w = ewsum * __builtin_amdgcn_rcpf(fmaxf((float)cnt, 1.f));
    float v = xln + fmaf(w, wev, xrn);
    float lk = fmaxf(v, 0.2f * v);
    float p = red1(lk * att2v);
    p += swz<0x401F>(p);
    float pe = __builtin_amdgcn_exp2f(p);
    ssum += pe;
    acc = fmaf(xln, pe, acc);
  }
  float outv = acc * __builtin_amdgcn_rcpf(ssum * (float)(cnt + 1));
  float o2 = outv + __shfl_xor(outv, 32);
  if (lane < 32)
    out_pre[wid * 32 + lane] = bfbits(0.5f * o2 + cbias[l * 32 + lane]);
}

// ---------------- BatchNorm stats (bf16 input) ----------------
__global__ __launch_bounds__(256) void stats_kernel(const unsigned short* __restrict__ out_pre,
                                                    float* __restrict__ gsum,
                                                    float* __restrict__ gsumsq) {
  int l = blockIdx.x >> 4, chunk = blockIdx.x & 15;
  int t = threadIdx.x;
  int c = t & 31, nsub = t >> 5;
  int n0 = chunk * 1250;
  float s1 = 0.f, s2 = 0.f;
  for (int n = n0 + nsub; n < n0 + 1250; n += 8) {
    float v = ldbf(out_pre, (l * N_NODES + n) * 32 + c);
    s1 += v; s2 += v * v;
  }
  __shared__ float l1[256], l2[256];
  l1[t] = s1; l2[t] = s2;
  __syncthreads();
  for (int off = 128; off >= 32; off >>= 1) {
    if (t < off) { l1[t] += l1[t + off]; l2[t] += l2[t + off]; }
    __syncthreads();
  }
  if (t < 32) {
    atomicAdd(&gsum[l * 32 + t], l1[t]);
    atomicAdd(&gsumsq[l * 32 + t], l2[t]);
  }
}

// ---------------- normalize + leaky relu -> bf16 [L][NPAD][32] ----------------
__global__ __launch_bounds__(256) void norm_kernel(const unsigned short* __restrict__ out_pre,
                                                   const float* __restrict__ gsum,
                                                   const float* __restrict__ gsumsq,
                                                   const float* __restrict__ gamma,
                                                   const float* __restrict__ beta,
                                                   unsigned short* __restrict__ hn) {
  int idx = blockIdx.x * 256 + threadIdx.x;
  int l = idx / (N_NODES * 8);
  int rem = idx - l * (N_NODES * 8);
  int n = rem >> 3, q = rem & 7;
  int c0 = q * 4;
  short4v v4 = *(const short4v*)(out_pre + (l * N_NODES + n) * 32 + c0);
  short4v o;
#pragma unroll
  for (int i = 0; i < 4; i++) {
    int c = c0 + i;
    float mu = gsum[l * 32 + c] * (1.f / N_NODES);
    float var = gsumsq[l * 32 + c] * (1.f / N_NODES) - mu * mu;
    float vv = __uint_as_float((unsigned)(unsigned short)v4[i] << 16);
    float v = gamma[l * 32 + c] * (vv - mu) * rsqrtf(var + EPS_BN) + beta[l * 32 + c];
    v = v > 0.f ? v : 0.01f * v;
    o[i] = (short)bfbits(v);
  }
  *(short4v*)(hn + ((size_t)l * NPAD + n) * 32 + c0) = o;
}

// --- GEMM1: h @ W1 -> relu -> per-colgroup 5-dot partials (non-atomic) ------
// each (block, wc) writes disjoint p[row][group][5]; group = blockIdx.x*2+wc
__global__ __launch_bounds__(256) void gemm1_kernel(const short* __restrict__ hn,
                                                    const short* __restrict__ W1bT,
                                                    const float* __restrict__ b1,
                                                    const float* __restrict__ W2,
                                                    float* __restrict__ p) {
  __shared__ __align__(16) short As[128 * 32];
  __shared__ __align__(16) short Bs[128 * 32];
  int t = threadIdx.x;
  int n0 = blockIdx.x * 128, m0 = blockIdx.y * 128;
  int wave = t >> 6, lane = t & 63;
  int wr = wave >> 1, wc = wave & 1;
  int mrow = lane & 15, quad = lane >> 4;
  floatx4 acc[4][4];
#pragma unroll
  for (int i = 0; i < 4; i++)
#pragma unroll
    for (int j = 0; j < 4; j++) acc[i][j] = (floatx4){0.f, 0.f, 0.f, 0.f};

  int r0 = t >> 2, s0 = t & 3;
  int r1 = (t + 256) >> 2, s1 = (t + 256) & 3;
  const short* aG0 = hn + (m0 + r0) * 32 + s0 * 8;
  const short* aG1 = hn + (m0 + r1) * 32 + s1 * 8;
  const short* bG0 = W1bT + (n0 + r0) * 800 + s0 * 8;
  const short* bG1 = W1bT + (n0 + r1) * 800 + s1 * 8;
  const int ak = NPAD * 32;
  short* aD0 = As + wave * 512;
  short* aD1 = As + 2048 + wave * 512;
  short* bD0 = Bs + wave * 512;
  short* bD1 = Bs + 2048 + wave * 512;

  for (int kt = 0; kt < 25; kt++) {
    gl_lds16(aG0, aD0);
    gl_lds16(aG1, aD1);
    gl_lds16(bG0, bD0);
    gl_lds16(bG1, bD1);
    aG0 += ak; aG1 += ak; bG0 += 32; bG1 += 32;
    __syncthreads();
    short8 af[4], bfr[4];
#pragma unroll
    for (int i = 0; i < 4; i++)
      af[i] = *(const short8*)(&As[(wr * 64 + i * 16 + mrow) * 32 + quad * 8]);
#pragma unroll
    for (int j = 0; j < 4; j++)
      bfr[j] = *(const short8*)(&Bs[(wc * 64 + j * 16 + mrow) * 32 + quad * 8]);
#pragma unroll
    for (int i = 0; i < 4; i++)
#pragma unroll
      for (int j = 0; j < 4; j++)
        acc[i][j] = __builtin_amdgcn_mfma_f32_16x16x32_bf16(af[i], bfr[j], acc[i][j], 0, 0, 0);
    __syncthreads();
  }

  // epilogue: relu+bias, 5-dot with W2, 16-lane DPP reduce, disjoint stores
  float w2v[4][5];
  float b1v[4];
#pragma unroll
  for (int j = 0; j < 4; j++) {
    int col = n0 + wc * 64 + j * 16 + mrow;
    bool ok = col < 800;
    b1v[j] = ok ? b1[col] : 0.f;
#pragma unroll
    for (int jj = 0; jj < 5; jj++) w2v[j][jj] = ok ? W2[col * 5 + jj] : 0.f;
  }
  int grp = blockIdx.x * 2 + wc;
#pragma unroll
  for (int i = 0; i < 4; i++) {
#pragma unroll
    for (int r = 0; r < 4; r++) {
      float s[5] = {0.f, 0.f, 0.f, 0.f, 0.f};
#pragma unroll
      for (int j = 0; j < 4; j++) {
        float v = fmaxf(acc[i][j][r] + b1v[j], 0.f);
#pragma unroll
        for (int jj = 0; jj < 5; jj++) s[jj] = fmaf(v, w2v[j][jj], s[jj]);
      }
#pragma unroll
      for (int jj = 0; jj < 5; jj++) {
        s[jj] = dpp_add<0xB1>(s[jj]);
        s[jj] = dpp_add<0x4E>(s[jj]);
        s[jj] = dpp_add<0x141>(s[jj]);
        s[jj] = dpp_add<0x140>(s[jj]);
      }
      int row = m0 + wr * 64 + i * 16 + quad * 4 + r;
      if (mrow == 0) {
#pragma unroll
        for (int jj = 0; jj < 5; jj++)
          p[(row * NGRP + grp) * 5 + jj] = s[jj];
      }
    }
  }
}

// ---- gemm2r: out[row][jj] = b2[jj] + sum_g p[row][g][jj] -------------------
__global__ __launch_bounds__(256) void gemm2r_kernel(const float* __restrict__ p,
                                                     const float* __restrict__ b2,
                                                     float* __restrict__ out) {
  int idx = blockIdx.x * 256 + threadIdx.x;
  if (idx >= N_NODES * 5) return;
  int row = idx / 5, jj = idx - row * 5;
  float s = b2[jj];
#pragma unroll
  for (int g = 0; g < NGRP; g++) s += p[(row * NGRP + g) * 5 + jj];
  out[idx] = s;
}

extern "C" void kernel_launch(void* const* d_in, const int* in_sizes, int n_in,
                              void* d_out, int out_size, void* d_ws, size_t ws_size,
                              hipStream_t stream) {
  const float* x    = (const float*)d_in[0];
  const int*   ei   = (const int*)d_in[1];
  const float* ew   = (const float*)d_in[2];
  const float* Wl   = (const float*)d_in[3];
  const float* bl   = (const float*)d_in[4];
  const float* Wr   = (const float*)d_in[5];
  const float* br   = (const float*)d_in[6];
  const float* We   = (const float*)d_in[7];
  const float* att  = (const float*)d_in[8];
  const float* cb   = (const float*)d_in[9];
  const float* gam  = (const float*)d_in[10];
  const float* bet  = (const float*)d_in[11];
  const float* W1   = (const float*)d_in[12];
  const float* b1   = (const float*)d_in[13];
  const float* W2   = (const float*)d_in[14];
  const float* b2   = (const float*)d_in[15];

  char* ws = (char*)d_ws;
  size_t off = 0;
  auto alloc = [&](size_t bytes) {
    void* p = ws + off;
    off = (off + bytes + 255) & ~(size_t)255;
    return p;
  };
  int* cnt     = (int*)alloc((size_t)NL_NN * 4);
  int* scn     = (int*)alloc((size_t)NL_NN * 4);
  int* btot    = (int*)alloc(SCAN_BLKS * 4);
  int* boff    = (int*)alloc(SCAN_BLKS * 4);
  int* rank    = (int*)alloc((size_t)TOTAL_E * 4);
  int* rowfin  = (int*)alloc((size_t)(NL_NN + 1) * 4);
  int2* ep     = (int2*)alloc((size_t)TOTAL_E * 8 + 64);  // +8 zero-pad records
  unsigned short* out_pre = (unsigned short*)alloc((size_t)NL_NN * 32 * 2);
  float* gsum   = (float*)alloc(N_LAYERS * 32 * 4);
  float* gsumsq = (float*)alloc(N_LAYERS * 32 * 4);
  unsigned short* xlb = (unsigned short*)alloc((size_t)NL_NN * 64 * 2);
  unsigned short* xrb = (unsigned short*)alloc((size_t)NL_NN * 64 * 2);
  __hip_bfloat16* w1t = (__hip_bfloat16*)alloc((size_t)896 * 800 * 2);
  float* pbuf = (float*)alloc((size_t)NPAD * NGRP * 5 * 4);  // 5.6 MB partials
  unsigned short* hn  = (unsigned short*)xlb;  // alias: xlb dead after attn

  prep_kernel<<<PREP_BLKS, 1024, 0, stream>>>(ei, x, Wl, bl, Wr, br, W1,
                                              cnt, rank, xlb, xrb, w1t);
  scan_a<<<SCAN_BLKS, 1024, 0, stream>>>(cnt, scn, btot, gsum, gsumsq);
  scan_b<<<1, 512, 0, stream>>>(btot, boff);
  fill_kernel<<<FILL_BLKS, 1024, 0, stream>>>(ei, ew, scn, boff, rank, rowfin, ep);
  attn_kernel<<<ATTN_BLKS, 256, 0, stream>>>(
      xlb, xrb, rowfin, ep, We, att, cb, out_pre);
  stats_kernel<<<N_LAYERS * 16, 256, 0, stream>>>(out_pre, gsum, gsumsq);
  norm_kernel<<<(NL_NN * 8) / 256, 256, 0, stream>>>(
      out_pre, gsum, gsumsq, gam, bet, hn);
  gemm1_kernel<<<dim3(7, 157), 256, 0, stream>>>(
      (const short*)hn, (const short*)w1t, b1, W2, pbuf);
  gemm2r_kernel<<<(N_NODES * 5 + 255) / 256, 256, 0, stream>>>(
      pbuf, b2, (float*)d_out);
}

// Round 3
// 500.505 us; speedup vs baseline: 1.1114x; 1.0743x over previous
//
#include <hip/hip_runtime.h>
#include <hip/hip_bf16.h>

#define N_NODES 20000
#define N_EDGES 100000
#define N_LAYERS 25
#define NPAD 20096   // 157*128
#define EPS_BN 1e-5f
#define LOG2E 1.44269504088896340736f
#define NL_NN (N_LAYERS * N_NODES)          // 500000
#define TOTAL_E (N_LAYERS * N_EDGES)        // 2500000
#define SCAN_BLKS ((NL_NN + 1023) / 1024)   // 489
#define QUARTER_N 5000
#define CNT_BLKS (N_LAYERS * 4)             // 100
#define W1T_END (CNT_BLKS + 700)            // 800
#define XPAD_END (W1T_END + 157)            // 957
#define HPAD_BLKS 75                        // 25*96*32 shorts / 1024
#define PREP_BLKS (XPAD_END + HPAD_BLKS)    // 1032
#define EDGE_BLKS ((TOTAL_E + 1023) / 1024) // 2442
#define FILL_BLKS (EDGE_BLKS + SCAN_BLKS)
#define NGRP 14                             // 7 col-blocks x 2 wc halves
#define ATTN_BLKS (NL_NN / 4)               // 125000 = 8 * 15625
#define ATTN_PER_XCD (ATTN_BLKS / 8)        // 15625

typedef short short8 __attribute__((ext_vector_type(8)));
typedef short short4v __attribute__((ext_vector_type(4)));
typedef float floatx4 __attribute__((ext_vector_type(4)));
typedef float float8v __attribute__((ext_vector_type(8)));
typedef int int8v __attribute__((ext_vector_type(8)));
typedef int int2v __attribute__((ext_vector_type(2)));

template <int PAT>
__device__ __forceinline__ float swz(float v) {
  return __int_as_float(__builtin_amdgcn_ds_swizzle(__float_as_int(v), PAT));
}

template <int CTRL>
__device__ __forceinline__ float dpp_add(float v) {
  int r = __builtin_amdgcn_update_dpp(0, __float_as_int(v), CTRL, 0xF, 0xF, true);
  return v + __int_as_float(r);
}

// int index on purpose: 32-bit address math
__device__ __forceinline__ float ldbf(const unsigned short* __restrict__ p, int idx) {
  return __uint_as_float((unsigned)p[idx] << 16);
}

__device__ __forceinline__ unsigned short bfbits(float v) {
  return __builtin_bit_cast(unsigned short, (__hip_bfloat16)v);
}

// async global->LDS, 16B per lane; LDS dest = wave-uniform base + lane*16
__device__ __forceinline__ void gl_lds16(const short* g, short* l) {
  __builtin_amdgcn_global_load_lds(
      (const __attribute__((address_space(1))) void*)g,
      (__attribute__((address_space(3))) void*)l, 16, 0, 0);
}

// scalar load of one 32B record + wait (single asm: wait inseparable)
__device__ __forceinline__ int8v sload8(const void* p) {
  int8v r;
  asm volatile(
      "s_load_dwordx8 %0, %1, 0x0\n\t"
      "s_waitcnt lgkmcnt(0)"
      : "=s"(r)
      : "s"(p));
  return r;
}

// scalar load of {start,end} pair
__device__ __forceinline__ void sload2(const void* p, int& a, int& b) {
  int2v r;
  asm volatile(
      "s_load_dwordx2 %0, %1, 0x0\n\t"
      "s_waitcnt lgkmcnt(0)"
      : "=s"(r)
      : "s"(p));
  a = r[0];
  b = r[1];
}

// scalar load of a 4-record chunk (128B) in one block; single wait
__device__ __forceinline__ void sload_chunk(const void* p, int8v& r0, int8v& r1,
                                            int8v& r2, int8v& r3) {
  asm volatile(
      "s_load_dwordx8 %0, %4, 0x0\n\t"
      "s_load_dwordx8 %1, %4, 0x20\n\t"
      "s_load_dwordx8 %2, %4, 0x40\n\t"
      "s_load_dwordx8 %3, %4, 0x60\n\t"
      "s_waitcnt lgkmcnt(0)"
      : "=s"(r0), "=s"(r1), "=s"(r2), "=s"(r3)
      : "s"(p));
}

// 4-chain interleaved 16-lane reduce: single-instruction DPP adds.
// 4-way interleave gives 3-instr gaps (>=2 wait states VALU->DPP);
// s_nop 1 guards asm entry/exit adjacency.
__device__ __forceinline__ void red4(float& p0, float& p1, float& p2, float& p3) {
  asm volatile(
      "s_nop 1\n\t"
      "v_add_f32_dpp %0, %0, %0 quad_perm:[1,0,3,2] row_mask:0xf bank_mask:0xf\n\t"
      "v_add_f32_dpp %1, %1, %1 quad_perm:[1,0,3,2] row_mask:0xf bank_mask:0xf\n\t"
      "v_add_f32_dpp %2, %2, %2 quad_perm:[1,0,3,2] row_mask:0xf bank_mask:0xf\n\t"
      "v_add_f32_dpp %3, %3, %3 quad_perm:[1,0,3,2] row_mask:0xf bank_mask:0xf\n\t"
      "v_add_f32_dpp %0, %0, %0 quad_perm:[2,3,0,1] row_mask:0xf bank_mask:0xf\n\t"
      "v_add_f32_dpp %1, %1, %1 quad_perm:[2,3,0,1] row_mask:0xf bank_mask:0xf\n\t"
      "v_add_f32_dpp %2, %2, %2 quad_perm:[2,3,0,1] row_mask:0xf bank_mask:0xf\n\t"
      "v_add_f32_dpp %3, %3, %3 quad_perm:[2,3,0,1] row_mask:0xf bank_mask:0xf\n\t"
      "v_add_f32_dpp %0, %0, %0 row_half_mirror row_mask:0xf bank_mask:0xf\n\t"
      "v_add_f32_dpp %1, %1, %1 row_half_mirror row_mask:0xf bank_mask:0xf\n\t"
      "v_add_f32_dpp %2, %2, %2 row_half_mirror row_mask:0xf bank_mask:0xf\n\t"
      "v_add_f32_dpp %3, %3, %3 row_half_mirror row_mask:0xf bank_mask:0xf\n\t"
      "v_add_f32_dpp %0, %0, %0 row_mirror row_mask:0xf bank_mask:0xf\n\t"
      "v_add_f32_dpp %1, %1, %1 row_mirror row_mask:0xf bank_mask:0xf\n\t"
      "v_add_f32_dpp %2, %2, %2 row_mirror row_mask:0xf bank_mask:0xf\n\t"
      "v_add_f32_dpp %3, %3, %3 row_mirror row_mask:0xf bank_mask:0xf\n\t"
      "s_nop 1"
      : "+v"(p0), "+v"(p1), "+v"(p2), "+v"(p3));
}

// single-chain 16-lane reduce (self-loop), s_nop 1 padding for DPP hazards
__device__ __forceinline__ float red1(float p) {
  asm volatile(
      "s_nop 1\n\t"
      "v_add_f32_dpp %0, %0, %0 quad_perm:[1,0,3,2] row_mask:0xf bank_mask:0xf\n\t"
      "s_nop 1\n\t"
      "v_add_f32_dpp %0, %0, %0 quad_perm:[2,3,0,1] row_mask:0xf bank_mask:0xf\n\t"
      "s_nop 1\n\t"
      "v_add_f32_dpp %0, %0, %0 row_half_mirror row_mask:0xf bank_mask:0xf\n\t"
      "s_nop 1\n\t"
      "v_add_f32_dpp %0, %0, %0 row_mirror row_mask:0xf bank_mask:0xf\n\t"
      "s_nop 1"
      : "+v"(p));
  return p;
}

// --- prep: count hist (rank capture) + W1^T + xpad copy + hn pad zero -------
__global__ __launch_bounds__(1024) void prep_kernel(
    const int* __restrict__ ei, const float* __restrict__ x,
    const float* __restrict__ W1, int* __restrict__ cnt,
    int* __restrict__ rank, float* __restrict__ xpad,
    __hip_bfloat16* __restrict__ W1bT, unsigned short* __restrict__ hn) {
  __shared__ int smem[QUARTER_N];  // 20 KB (count hist); w1t reuses as float tile
  int b = blockIdx.x;
  if (b < CNT_BLKS) {
    int l = b >> 2, base = (b & 3) * QUARTER_N;
    for (int i = threadIdx.x; i < QUARTER_N; i += 1024) smem[i] = 0;
    __syncthreads();
    const int* dstp = ei + (size_t)l * 2 * N_EDGES + N_EDGES;
    int* rkp = rank + l * N_EDGES;
    for (int e = threadIdx.x; e < N_EDGES; e += 1024) {
      int d = dstp[e] - base;
      if ((unsigned)d < (unsigned)QUARTER_N) rkp[e] = atomicAdd(&smem[d], 1);
    }
    __syncthreads();
    int* outp = cnt + l * N_NODES + base;
    for (int i = threadIdx.x; i < QUARTER_N; i += 1024) outp[i] = smem[i];
  } else if (b < W1T_END) {
    float* tile = (float*)smem;  // [32][33]
    int bb = b - CNT_BLKS;
    int j0 = (bb % 28) * 32, k0 = (bb / 28) * 32;
    int tx = threadIdx.x & 31, ty = threadIdx.x >> 5;
    tile[ty * 33 + tx] = (j0 + tx < 800) ? W1[(k0 + ty) * 800 + j0 + tx] : 0.f;
    __syncthreads();
    W1bT[(size_t)(j0 + ty) * 800 + k0 + tx] = (__hip_bfloat16)tile[tx * 33 + ty];
  } else if (b < XPAD_END) {
    int idx = (b - W1T_END) * 1024 + threadIdx.x;
    if (idx < N_NODES * 8) {
      int nn = idx >> 3, k = idx & 7;
      xpad[idx] = (k < 5) ? x[nn * 5 + k] : 0.f;
    }
  } else {
    // zero hn pad rows (N_NODES..NPAD) so gemm1 reads finite values
    int idx = (b - XPAD_END) * 1024 + threadIdx.x;
    const int per_l = (NPAD - N_NODES) * 32;  // 3072
    if (idx < N_LAYERS * per_l) {
      int l = idx / per_l;
      int rem = idx - l * per_l;
      hn[((size_t)l * NPAD + N_NODES) * 32 + rem] = 0;
    }
  }
}

// -------- scan_a: per-block scan; also zero gsum/gsumsq ---------------------
__global__ __launch_bounds__(1024) void scan_a(const int* __restrict__ cnt,
                                               int* __restrict__ scn,
                                               int* __restrict__ btot,
                                               float* __restrict__ gsum,
                                               float* __restrict__ gsumsq) {
  int t = threadIdx.x, b = blockIdx.x;
  int i = b * 1024 + t;
  int lane = t & 63, wv = t >> 6;
  int v = (i < NL_NN) ? cnt[i] : 0;
  int sc = v;
#pragma unroll
  for (int off = 1; off < 64; off <<= 1) {
    int u = __shfl_up(sc, off);
    if (lane >= off) sc += u;
  }
  __shared__ int ws[16];
  if (lane == 63) ws[wv] = sc;
  __syncthreads();
  if (t < 16) {
    int xx = ws[t];
#pragma unroll
    for (int off = 1; off < 16; off <<= 1) {
      int u = __shfl_up(xx, off);
      if (t >= off) xx += u;
    }
    ws[t] = xx;
  }
  __syncthreads();
  int bofs = wv ? ws[wv - 1] : 0;
  if (i < NL_NN) scn[i] = bofs + sc - v;
  if (t == 0) btot[b] = ws[15];
  if (b == 200 && t < N_LAYERS * 32) {
    gsum[t] = 0.f;
    gsumsq[t] = 0.f;
  }
}

__global__ __launch_bounds__(512) void scan_b(const int* __restrict__ btot,
                                              int* __restrict__ boff) {
  int t = threadIdx.x;
  int lane = t & 63, wv = t >> 6;
  int v = (t < SCAN_BLKS) ? btot[t] : 0;
  int sc = v;
#pragma unroll
  for (int off = 1; off < 64; off <<= 1) {
    int u = __shfl_up(sc, off);
    if (lane >= off) sc += u;
  }
  __shared__ int ws[8];
  if (lane == 63) ws[wv] = sc;
  __syncthreads();
  if (t < 8) {
    int xx = ws[t];
#pragma unroll
    for (int off = 1; off < 8; off <<= 1) {
      int u = __shfl_up(xx, off);
      if (t >= off) xx += u;
    }
    ws[t] = xx;
  }
  __syncthreads();
  int bofs = wv ? ws[wv - 1] : 0;
  if (t < SCAN_BLKS) boff[t] = bofs + sc - v;
}

// ------- fill: edge-parallel, atomic-free; 32B records {w, x0..x4, 0, 0} ----
// tail builds rowse {start,end} and zero-pads 4 records past TOTAL_E
__global__ __launch_bounds__(1024) void fill_kernel(const int* __restrict__ ei,
                                                    const float* __restrict__ ew,
                                                    const int* __restrict__ scn,
                                                    const int* __restrict__ boff,
                                                    const int* __restrict__ rank,
                                                    const float* __restrict__ xpad,
                                                    int2* __restrict__ rowse,
                                                    float* __restrict__ epf) {
  int b = blockIdx.x;
  if (b < EDGE_BLKS) {
    int idx = b * 1024 + threadIdx.x;
    if (idx >= TOTAL_E) return;
    int l = idx / N_EDGES, e = idx - l * N_EDGES;
    int src = ei[(size_t)l * 2 * N_EDGES + e];
    int dst = ei[(size_t)l * 2 * N_EDGES + N_EDGES + e];
    int g = l * N_NODES + dst;
    int pos = scn[g] + boff[g >> 10] + rank[idx];
    float w = ew[(size_t)l * N_EDGES + e];
    float4 xv = *(const float4*)(xpad + (size_t)src * 8);
    float x4v = xpad[(size_t)src * 8 + 4];
    float8v r;
    r[0] = w; r[1] = xv.x; r[2] = xv.y; r[3] = xv.z; r[4] = xv.w; r[5] = x4v;
    r[6] = 0.f; r[7] = 0.f;
    *(float8v*)(epf + (size_t)pos * 8) = r;
  } else {
    int i = (b - EDGE_BLKS) * 1024 + threadIdx.x;
    if (i < NL_NN) {
      int st = scn[i] + boff[i >> 10];
      int en = (i + 1 < NL_NN) ? scn[i + 1] + boff[(i + 1) >> 10] : TOTAL_E;
      rowse[i] = make_int2(st, en);
    }
    if (i < 4) {
      float8v z = {0.f, 0.f, 0.f, 0.f, 0.f, 0.f, 0.f, 0.f};
      *(float8v*)(epf + (size_t)(TOTAL_E + i) * 8) = z;
    }
  }
}

// ---------------- fused GAT layer: 1 wave per (layer,node) ------------------
// gather-free: edge records carry x[src] inline; xa reconstructed via 5 FMA
// from SGPR multipliers. Inner loop has ZERO vector-memory ops; all edge data
// flows through the scalar pipe (sequential 32B records, K$-line friendly).
// wid forced scalar via readfirstlane so record pointers live in SGPRs.
__global__ __launch_bounds__(256) void attn_kernel(
    const float* __restrict__ xpad, const int2* __restrict__ rowse,
    const float* __restrict__ epf,
    const float* __restrict__ Wl, const float* __restrict__ bl,
    const float* __restrict__ Wr, const float* __restrict__ br,
    const float* __restrict__ We, const float* __restrict__ att,
    const float* __restrict__ cbias, unsigned short* __restrict__ out_pre) {
  int b = blockIdx.x;
  int nb = (b & 7) * ATTN_PER_XCD + (b >> 3);  // bijective XCD-chunk swizzle
  // wave-uniform by construction; readfirstlane makes it SGPR for the compiler
  int wid = __builtin_amdgcn_readfirstlane(nb * 4 + (threadIdx.x >> 6));
  int lane = threadIdx.x & 63;
  int l = wid / N_NODES, n = wid - l * N_NODES;

  // layer params (L1-hot: shared by all waves of the layer)
  float wlv0 = Wl[(l * 5 + 0) * 64 + lane];
  float wlv1 = Wl[(l * 5 + 1) * 64 + lane];
  float wlv2 = Wl[(l * 5 + 2) * 64 + lane];
  float wlv3 = Wl[(l * 5 + 3) * 64 + lane];
  float wlv4 = Wl[(l * 5 + 4) * 64 + lane];
  float blv = bl[l * 64 + lane];
  float wev = We[l * 64 + lane];
  float att2v = att[l * 64 + lane] * LOG2E;

  int s_, e_;
  sload2(rowse + wid, s_, e_);
  int cnt = e_ - s_;

  // own-node transforms from scalar x row
  int8v xn = sload8(xpad + (size_t)n * 8);
  float xrn = br[l * 64 + lane];
  float xln = blv;
  {
    float wr0 = Wr[(l * 5 + 0) * 64 + lane];
    float wr1 = Wr[(l * 5 + 1) * 64 + lane];
    float wr2 = Wr[(l * 5 + 2) * 64 + lane];
    float wr3 = Wr[(l * 5 + 3) * 64 + lane];
    float wr4 = Wr[(l * 5 + 4) * 64 + lane];
    float x0 = __int_as_float(xn[0]), x1 = __int_as_float(xn[1]);
    float x2 = __int_as_float(xn[2]), x3 = __int_as_float(xn[3]);
    float x4 = __int_as_float(xn[4]);
    xrn = fmaf(x0, wr0, xrn); xrn = fmaf(x1, wr1, xrn);
    xrn = fmaf(x2, wr2, xrn); xrn = fmaf(x3, wr3, xrn);
    xrn = fmaf(x4, wr4, xrn);
    xln = fmaf(x0, wlv0, xln); xln = fmaf(x1, wlv1, xln);
    xln = fmaf(x2, wlv2, xln); xln = fmaf(x3, wlv3, xln);
    xln = fmaf(x4, wlv4, xln);
  }

  float ssum = 0.f, acc = 0.f, ewsum = 0.f;
  int nchunk = (cnt + 3) >> 2;
  const float* pch = epf + (size_t)s_ * 8;
  for (int c = 0; c < nchunk; c++) {
    int8v r0, r1, r2, r3;
    sload_chunk(pch, r0, r1, r2, r3);
    pch += 32;
    int m = cnt - c * 4;  // valid edges this chunk
    float xa[4], pk[4], wv[4];
#pragma unroll
    for (int k = 0; k < 4; k++) {
      int8v rr = (k == 0) ? r0 : (k == 1) ? r1 : (k == 2) ? r2 : r3;
      bool ok = k < m;                       // wave-uniform -> s_cselect
      int wbits = ok ? rr[0] : 0;
      wv[k] = __int_as_float(wbits);
      float a = fmaf(__int_as_float(rr[1]), wlv0, blv);
      a = fmaf(__int_as_float(rr[2]), wlv1, a);
      a = fmaf(__int_as_float(rr[3]), wlv2, a);
      a = fmaf(__int_as_float(rr[4]), wlv3, a);
      a = fmaf(__int_as_float(rr[5]), wlv4, a);
      xa[k] = a;
      float bias = __int_as_float(ok ? 0 : (int)0xff800000);  // -inf mask
      float v = a + fmaf(wv[k], wev, xrn);
      float lk = fmaxf(v, 0.2f * v);
      pk[k] = fmaf(lk, att2v, bias);
    }
    red4(pk[0], pk[1], pk[2], pk[3]);
#pragma unroll
    for (int k = 0; k < 4; k++) pk[k] += swz<0x401F>(pk[k]);
#pragma unroll
    for (int k = 0; k < 4; k++) {
      float pe = __builtin_amdgcn_exp2f(pk[k]);
      ssum += pe;
      acc = fmaf(xa[k], pe, acc);
      ewsum += wv[k];
    }
  }
  // self-loop edge with mean incoming weight
  {
    float w = ewsum * __builtin_amdgcn_rcpf(fmaxf((float)cnt, 1.f));
    float v = xln + fmaf(w, wev, xrn);
    float lk = fmaxf(v, 0.2f * v);
    float p = red1(lk * att2v);
    p += swz<0x401F>(p);
    float pe = __builtin_amdgcn_exp2f(p);
    ssum += pe;
    acc = fmaf(xln, pe, acc);
  }
  float outv = acc * __builtin_amdgcn_rcpf(ssum * (float)(cnt + 1));
  float o2 = outv + __shfl_xor(outv, 32);
  if (lane < 32)
    out_pre[wid * 32 + lane] = bfbits(0.5f * o2 + cbias[l * 32 + lane]);
}

// ---------------- BatchNorm stats (bf16 input) ----------------
__global__ __launch_bounds__(256) void stats_kernel(const unsigned short* __restrict__ out_pre,
                                                    float* __restrict__ gsum,
                                                    float* __restrict__ gsumsq) {
  int l = blockIdx.x >> 4, chunk = blockIdx.x & 15;
  int t = threadIdx.x;
  int c = t & 31, nsub = t >> 5;
  int n0 = chunk * 1250;
  float s1 = 0.f, s2 = 0.f;
  for (int n = n0 + nsub; n < n0 + 1250; n += 8) {
    float v = ldbf(out_pre, (l * N_NODES + n) * 32 + c);
    s1 += v; s2 += v * v;
  }
  __shared__ float l1[256], l2[256];
  l1[t] = s1; l2[t] = s2;
  __syncthreads();
  for (int off = 128; off >= 32; off >>= 1) {
    if (t < off) { l1[t] += l1[t + off]; l2[t] += l2[t + off]; }
    __syncthreads();
  }
  if (t < 32) {
    atomicAdd(&gsum[l * 32 + t], l1[t]);
    atomicAdd(&gsumsq[l * 32 + t], l2[t]);
  }
}

// ---------------- normalize + leaky relu -> bf16 [L][NPAD][32] ----------------
__global__ __launch_bounds__(256) void norm_kernel(const unsigned short* __restrict__ out_pre,
                                                   const float* __restrict__ gsum,
                                                   const float* __restrict__ gsumsq,
                                                   const float* __restrict__ gamma,
                                                   const float* __restrict__ beta,
                                                   unsigned short* __restrict__ hn) {
  int idx = blockIdx.x * 256 + threadIdx.x;
  int l = idx / (N_NODES * 8);
  int rem = idx - l * (N_NODES * 8);
  int n = rem >> 3, q = rem & 7;
  int c0 = q * 4;
  short4v v4 = *(const short4v*)(out_pre + (l * N_NODES + n) * 32 + c0);
  short4v o;
#pragma unroll
  for (int i = 0; i < 4; i++) {
    int c = c0 + i;
    float mu = gsum[l * 32 + c] * (1.f / N_NODES);
    float var = gsumsq[l * 32 + c] * (1.f / N_NODES) - mu * mu;
    float vv = __uint_as_float((unsigned)(unsigned short)v4[i] << 16);
    float v = gamma[l * 32 + c] * (vv - mu) * rsqrtf(var + EPS_BN) + beta[l * 32 + c];
    v = v > 0.f ? v : 0.01f * v;
    o[i] = (short)bfbits(v);
  }
  *(short4v*)(hn + ((size_t)l * NPAD + n) * 32 + c0) = o;
}

// --- GEMM1: h @ W1 -> relu -> per-colgroup 5-dot partials (non-atomic) ------
// each (block, wc) writes disjoint p[row][group][5]; group = blockIdx.x*2+wc
__global__ __launch_bounds__(256) void gemm1_kernel(const short* __restrict__ hn,
                                                    const short* __restrict__ W1bT,
                                                    const float* __restrict__ b1,
                                                    const float* __restrict__ W2,
                                                    float* __restrict__ p) {
  __shared__ __align__(16) short As[128 * 32];
  __shared__ __align__(16) short Bs[128 * 32];
  int t = threadIdx.x;
  int n0 = blockIdx.x * 128, m0 = blockIdx.y * 128;
  int wave = t >> 6, lane = t & 63;
  int wr = wave >> 1, wc = wave & 1;
  int mrow = lane & 15, quad = lane >> 4;
  floatx4 acc[4][4];
#pragma unroll
  for (int i = 0; i < 4; i++)
#pragma unroll
    for (int j = 0; j < 4; j++) acc[i][j] = (floatx4){0.f, 0.f, 0.f, 0.f};

  int r0 = t >> 2, s0 = t & 3;
  int r1 = (t + 256) >> 2, s1 = (t + 256) & 3;
  const short* aG0 = hn + (m0 + r0) * 32 + s0 * 8;
  const short* aG1 = hn + (m0 + r1) * 32 + s1 * 8;
  const short* bG0 = W1bT + (n0 + r0) * 800 + s0 * 8;
  const short* bG1 = W1bT + (n0 + r1) * 800 + s1 * 8;
  const int ak = NPAD * 32;
  short* aD0 = As + wave * 512;
  short* aD1 = As + 2048 + wave * 512;
  short* bD0 = Bs + wave * 512;
  short* bD1 = Bs + 2048 + wave * 512;

  for (int kt = 0; kt < 25; kt++) {
    gl_lds16(aG0, aD0);
    gl_lds16(aG1, aD1);
    gl_lds16(bG0, bD0);
    gl_lds16(bG1, bD1);
    aG0 += ak; aG1 += ak; bG0 += 32; bG1 += 32;
    __syncthreads();
    short8 af[4], bfr[4];
#pragma unroll
    for (int i = 0; i < 4; i++)
      af[i] = *(const short8*)(&As[(wr * 64 + i * 16 + mrow) * 32 + quad * 8]);
#pragma unroll
    for (int j = 0; j < 4; j++)
      bfr[j] = *(const short8*)(&Bs[(wc * 64 + j * 16 + mrow) * 32 + quad * 8]);
#pragma unroll
    for (int i = 0; i < 4; i++)
#pragma unroll
      for (int j = 0; j < 4; j++)
        acc[i][j] = __builtin_amdgcn_mfma_f32_16x16x32_bf16(af[i], bfr[j], acc[i][j], 0, 0, 0);
    __syncthreads();
  }

  // epilogue: relu+bias, 5-dot with W2, 16-lane DPP reduce, disjoint stores
  float w2v[4][5];
  float b1v[4];
#pragma unroll
  for (int j = 0; j < 4; j++) {
    int col = n0 + wc * 64 + j * 16 + mrow;
    bool ok = col < 800;
    b1v[j] = ok ? b1[col] : 0.f;
#pragma unroll
    for (int jj = 0; jj < 5; jj++) w2v[j][jj] = ok ? W2[col * 5 + jj] : 0.f;
  }
  int grp = blockIdx.x * 2 + wc;
#pragma unroll
  for (int i = 0; i < 4; i++) {
#pragma unroll
    for (int r = 0; r < 4; r++) {
      float s[5] = {0.f, 0.f, 0.f, 0.f, 0.f};
#pragma unroll
      for (int j = 0; j < 4; j++) {
        float v = fmaxf(acc[i][j][r] + b1v[j], 0.f);
#pragma unroll
        for (int jj = 0; jj < 5; jj++) s[jj] = fmaf(v, w2v[j][jj], s[jj]);
      }
#pragma unroll
      for (int jj = 0; jj < 5; jj++) {
        s[jj] = dpp_add<0xB1>(s[jj]);
        s[jj] = dpp_add<0x4E>(s[jj]);
        s[jj] = dpp_add<0x141>(s[jj]);
        s[jj] = dpp_add<0x140>(s[jj]);
      }
      int row = m0 + wr * 64 + i * 16 + quad * 4 + r;
      if (mrow == 0) {
#pragma unroll
        for (int jj = 0; jj < 5; jj++)
          p[(row * NGRP + grp) * 5 + jj] = s[jj];
      }
    }
  }
}

// ---- gemm2r: out[row][jj] = b2[jj] + sum_g p[row][g][jj] -------------------
__global__ __launch_bounds__(256) void gemm2r_kernel(const float* __restrict__ p,
                                                     const float* __restrict__ b2,
                                                     float* __restrict__ out) {
  int idx = blockIdx.x * 256 + threadIdx.x;
  if (idx >= N_NODES * 5) return;
  int row = idx / 5, jj = idx - row * 5;
  float s = b2[jj];
#pragma unroll
  for (int g = 0; g < NGRP; g++) s += p[(row * NGRP + g) * 5 + jj];
  out[idx] = s;
}

extern "C" void kernel_launch(void* const* d_in, const int* in_sizes, int n_in,
                              void* d_out, int out_size, void* d_ws, size_t ws_size,
                              hipStream_t stream) {
  const float* x    = (const float*)d_in[0];
  const int*   ei   = (const int*)d_in[1];
  const float* ew   = (const float*)d_in[2];
  const float* Wl   = (const float*)d_in[3];
  const float* bl   = (const float*)d_in[4];
  const float* Wr   = (const float*)d_in[5];
  const float* br   = (const float*)d_in[6];
  const float* We   = (const float*)d_in[7];
  const float* att  = (const float*)d_in[8];
  const float* cb   = (const float*)d_in[9];
  const float* gam  = (const float*)d_in[10];
  const float* bet  = (const float*)d_in[11];
  const float* W1   = (const float*)d_in[12];
  const float* b1   = (const float*)d_in[13];
  const float* W2   = (const float*)d_in[14];
  const float* b2   = (const float*)d_in[15];

  char* ws = (char*)d_ws;
  size_t off = 0;
  auto alloc = [&](size_t bytes) {
    void* p = ws + off;
    off = (off + bytes + 255) & ~(size_t)255;
    return p;
  };
  int* cnt     = (int*)alloc((size_t)NL_NN * 4);
  int* scn     = (int*)alloc((size_t)NL_NN * 4);
  int* btot    = (int*)alloc(SCAN_BLKS * 4);
  int* boff    = (int*)alloc(SCAN_BLKS * 4);
  int* rank    = (int*)alloc((size_t)TOTAL_E * 4);
  int2* rowse  = (int2*)alloc((size_t)NL_NN * 8);
  float* epf   = (float*)alloc((size_t)TOTAL_E * 32 + 128);  // 32B recs + pad
  unsigned short* out_pre = (unsigned short*)alloc((size_t)NL_NN * 32 * 2);
  float* gsum   = (float*)alloc(N_LAYERS * 32 * 4);
  float* gsumsq = (float*)alloc(N_LAYERS * 32 * 4);
  float* xpad   = (float*)alloc((size_t)N_NODES * 8 * 4);
  __hip_bfloat16* w1t = (__hip_bfloat16*)alloc((size_t)896 * 800 * 2);
  float* pbuf = (float*)alloc((size_t)NPAD * NGRP * 5 * 4);  // 5.6 MB partials
  unsigned short* hn = (unsigned short*)alloc((size_t)N_LAYERS * NPAD * 32 * 2);

  prep_kernel<<<PREP_BLKS, 1024, 0, stream>>>(ei, x, W1, cnt, rank, xpad, w1t, hn);
  scan_a<<<SCAN_BLKS, 1024, 0, stream>>>(cnt, scn, btot, gsum, gsumsq);
  scan_b<<<1, 512, 0, stream>>>(btot, boff);
  fill_kernel<<<FILL_BLKS, 1024, 0, stream>>>(ei, ew, scn, boff, rank, xpad,
                                              rowse, epf);
  attn_kernel<<<ATTN_BLKS, 256, 0, stream>>>(
      xpad, rowse, epf, Wl, bl, Wr, br, We, att, cb, out_pre);
  stats_kernel<<<N_LAYERS * 16, 256, 0, stream>>>(out_pre, gsum, gsumsq);
  norm_kernel<<<(NL_NN * 8) / 256, 256, 0, stream>>>(
      out_pre, gsum, gsumsq, gam, bet, hn);
  gemm1_kernel<<<dim3(7, 157), 256, 0, stream>>>(
      (const short*)hn, (const short*)w1t, b1, W2, pbuf);
  gemm2r_kernel<<<(N_NODES * 5 + 255) / 256, 256, 0, stream>>>(
      pbuf, b2, (float*)d_out);
}

// Round 4
// 496.747 us; speedup vs baseline: 1.1198x; 1.0076x over previous
//
#include <hip/hip_runtime.h>
#include <hip/hip_bf16.h>

#define N_NODES 20000
#define N_EDGES 100000
#define N_LAYERS 25
#define NPAD 20096   // 157*128
#define EPS_BN 1e-5f
#define LOG2E 1.44269504088896340736f
#define NL_NN (N_LAYERS * N_NODES)          // 500000
#define TOTAL_E (N_LAYERS * N_EDGES)        // 2500000
#define SCAN_BLKS ((NL_NN + 1023) / 1024)   // 489
#define QUARTER_N 5000
#define CNT_BLKS (N_LAYERS * 4)             // 100
#define W1T_END (CNT_BLKS + 700)            // 800
#define XPAD_END (W1T_END + 157)            // 957
#define HPAD_BLKS 75                        // 25*96*32 shorts / 1024
#define PREP_BLKS (XPAD_END + HPAD_BLKS)    // 1032
#define EDGE_BLKS ((TOTAL_E + 1023) / 1024) // 2442
#define FILL_BLKS (EDGE_BLKS + SCAN_BLKS)
#define NGRP 14                             // 7 col-blocks x 2 wc halves
#define NPW 8                               // nodes per wave
#define NPL (N_NODES / NPW)                 // 2500 waves per layer
#define ATTN_WAVES (NL_NN / NPW)            // 62500
#define ATTN_BLKS (ATTN_WAVES / 4)          // 15625

typedef short short8 __attribute__((ext_vector_type(8)));
typedef short short4v __attribute__((ext_vector_type(4)));
typedef float floatx4 __attribute__((ext_vector_type(4)));
typedef float float8v __attribute__((ext_vector_type(8)));
typedef int int8v __attribute__((ext_vector_type(8)));
typedef int int2v __attribute__((ext_vector_type(2)));

template <int PAT>
__device__ __forceinline__ float swz(float v) {
  return __int_as_float(__builtin_amdgcn_ds_swizzle(__float_as_int(v), PAT));
}

template <int CTRL>
__device__ __forceinline__ float dpp_add(float v) {
  int r = __builtin_amdgcn_update_dpp(0, __float_as_int(v), CTRL, 0xF, 0xF, true);
  return v + __int_as_float(r);
}

// int index on purpose: 32-bit address math
__device__ __forceinline__ float ldbf(const unsigned short* __restrict__ p, int idx) {
  return __uint_as_float((unsigned)p[idx] << 16);
}

__device__ __forceinline__ unsigned short bfbits(float v) {
  return __builtin_bit_cast(unsigned short, (__hip_bfloat16)v);
}

// async global->LDS, 16B per lane; LDS dest = wave-uniform base + lane*16
__device__ __forceinline__ void gl_lds16(const short* g, short* l) {
  __builtin_amdgcn_global_load_lds(
      (const __attribute__((address_space(1))) void*)g,
      (__attribute__((address_space(3))) void*)l, 16, 0, 0);
}

// scalar load of one 32B record + wait (single asm: wait inseparable)
__device__ __forceinline__ int8v sload8(const void* p) {
  int8v r;
  asm volatile(
      "s_load_dwordx8 %0, %1, 0x0\n\t"
      "s_waitcnt lgkmcnt(0)"
      : "=s"(r)
      : "s"(p));
  return r;
}

// scalar load of 16 ints (two dwordx8, 32B-aligned) + wait
__device__ __forceinline__ void sload_rp(const void* p, int8v& a, int8v& b) {
  asm volatile(
      "s_load_dwordx8 %0, %2, 0x0\n\t"
      "s_load_dwordx8 %1, %2, 0x20\n\t"
      "s_waitcnt lgkmcnt(0)"
      : "=s"(a), "=s"(b)
      : "s"(p));
}

// scalar load of a 4-record chunk (128B) in one block; single wait
__device__ __forceinline__ void sload_chunk(const void* p, int8v& r0, int8v& r1,
                                            int8v& r2, int8v& r3) {
  asm volatile(
      "s_load_dwordx8 %0, %4, 0x0\n\t"
      "s_load_dwordx8 %1, %4, 0x20\n\t"
      "s_load_dwordx8 %2, %4, 0x40\n\t"
      "s_load_dwordx8 %3, %4, 0x60\n\t"
      "s_waitcnt lgkmcnt(0)"
      : "=s"(r0), "=s"(r1), "=s"(r2), "=s"(r3)
      : "s"(p));
}

// 4-chain interleaved 16-lane reduce: single-instruction DPP adds.
// 4-way interleave gives 3-instr gaps (>=2 wait states VALU->DPP);
// s_nop 1 guards asm entry/exit adjacency.
__device__ __forceinline__ void red4(float& p0, float& p1, float& p2, float& p3) {
  asm volatile(
      "s_nop 1\n\t"
      "v_add_f32_dpp %0, %0, %0 quad_perm:[1,0,3,2] row_mask:0xf bank_mask:0xf\n\t"
      "v_add_f32_dpp %1, %1, %1 quad_perm:[1,0,3,2] row_mask:0xf bank_mask:0xf\n\t"
      "v_add_f32_dpp %2, %2, %2 quad_perm:[1,0,3,2] row_mask:0xf bank_mask:0xf\n\t"
      "v_add_f32_dpp %3, %3, %3 quad_perm:[1,0,3,2] row_mask:0xf bank_mask:0xf\n\t"
      "v_add_f32_dpp %0, %0, %0 quad_perm:[2,3,0,1] row_mask:0xf bank_mask:0xf\n\t"
      "v_add_f32_dpp %1, %1, %1 quad_perm:[2,3,0,1] row_mask:0xf bank_mask:0xf\n\t"
      "v_add_f32_dpp %2, %2, %2 quad_perm:[2,3,0,1] row_mask:0xf bank_mask:0xf\n\t"
      "v_add_f32_dpp %3, %3, %3 quad_perm:[2,3,0,1] row_mask:0xf bank_mask:0xf\n\t"
      "v_add_f32_dpp %0, %0, %0 row_half_mirror row_mask:0xf bank_mask:0xf\n\t"
      "v_add_f32_dpp %1, %1, %1 row_half_mirror row_mask:0xf bank_mask:0xf\n\t"
      "v_add_f32_dpp %2, %2, %2 row_half_mirror row_mask:0xf bank_mask:0xf\n\t"
      "v_add_f32_dpp %3, %3, %3 row_half_mirror row_mask:0xf bank_mask:0xf\n\t"
      "v_add_f32_dpp %0, %0, %0 row_mirror row_mask:0xf bank_mask:0xf\n\t"
      "v_add_f32_dpp %1, %1, %1 row_mirror row_mask:0xf bank_mask:0xf\n\t"
      "v_add_f32_dpp %2, %2, %2 row_mirror row_mask:0xf bank_mask:0xf\n\t"
      "v_add_f32_dpp %3, %3, %3 row_mirror row_mask:0xf bank_mask:0xf\n\t"
      "s_nop 1"
      : "+v"(p0), "+v"(p1), "+v"(p2), "+v"(p3));
}

// single-chain 16-lane reduce (self-loop), s_nop 1 padding for DPP hazards
__device__ __forceinline__ float red1(float p) {
  asm volatile(
      "s_nop 1\n\t"
      "v_add_f32_dpp %0, %0, %0 quad_perm:[1,0,3,2] row_mask:0xf bank_mask:0xf\n\t"
      "s_nop 1\n\t"
      "v_add_f32_dpp %0, %0, %0 quad_perm:[2,3,0,1] row_mask:0xf bank_mask:0xf\n\t"
      "s_nop 1\n\t"
      "v_add_f32_dpp %0, %0, %0 row_half_mirror row_mask:0xf bank_mask:0xf\n\t"
      "s_nop 1\n\t"
      "v_add_f32_dpp %0, %0, %0 row_mirror row_mask:0xf bank_mask:0xf\n\t"
      "s_nop 1"
      : "+v"(p));
  return p;
}

// --- prep: count hist (rank capture) + W1^T + xpad copy + hn pad zero -------
__global__ __launch_bounds__(1024) void prep_kernel(
    const int* __restrict__ ei, const float* __restrict__ x,
    const float* __restrict__ W1, int* __restrict__ cnt,
    int* __restrict__ rank, float* __restrict__ xpad,
    __hip_bfloat16* __restrict__ W1bT, unsigned short* __restrict__ hn) {
  __shared__ int smem[QUARTER_N];  // 20 KB (count hist); w1t reuses as float tile
  int b = blockIdx.x;
  if (b < CNT_BLKS) {
    int l = b >> 2, base = (b & 3) * QUARTER_N;
    for (int i = threadIdx.x; i < QUARTER_N; i += 1024) smem[i] = 0;
    __syncthreads();
    const int* dstp = ei + (size_t)l * 2 * N_EDGES + N_EDGES;
    int* rkp = rank + l * N_EDGES;
    for (int e = threadIdx.x; e < N_EDGES; e += 1024) {
      int d = dstp[e] - base;
      if ((unsigned)d < (unsigned)QUARTER_N) rkp[e] = atomicAdd(&smem[d], 1);
    }
    __syncthreads();
    int* outp = cnt + l * N_NODES + base;
    for (int i = threadIdx.x; i < QUARTER_N; i += 1024) outp[i] = smem[i];
  } else if (b < W1T_END) {
    float* tile = (float*)smem;  // [32][33]
    int bb = b - CNT_BLKS;
    int j0 = (bb % 28) * 32, k0 = (bb / 28) * 32;
    int tx = threadIdx.x & 31, ty = threadIdx.x >> 5;
    tile[ty * 33 + tx] = (j0 + tx < 800) ? W1[(k0 + ty) * 800 + j0 + tx] : 0.f;
    __syncthreads();
    W1bT[(size_t)(j0 + ty) * 800 + k0 + tx] = (__hip_bfloat16)tile[tx * 33 + ty];
  } else if (b < XPAD_END) {
    int idx = (b - W1T_END) * 1024 + threadIdx.x;
    if (idx < N_NODES * 8) {
      int nn = idx >> 3, k = idx & 7;
      xpad[idx] = (k < 5) ? x[nn * 5 + k] : 0.f;
    }
  } else {
    // zero hn pad rows (N_NODES..NPAD) so gemm1 reads finite values
    int idx = (b - XPAD_END) * 1024 + threadIdx.x;
    const int per_l = (NPAD - N_NODES) * 32;  // 3072
    if (idx < N_LAYERS * per_l) {
      int l = idx / per_l;
      int rem = idx - l * per_l;
      hn[((size_t)l * NPAD + N_NODES) * 32 + rem] = 0;
    }
  }
}

// -------- scan_a: per-block scan; also zero gsum/gsumsq ---------------------
__global__ __launch_bounds__(1024) void scan_a(const int* __restrict__ cnt,
                                               int* __restrict__ scn,
                                               int* __restrict__ btot,
                                               float* __restrict__ gsum,
                                               float* __restrict__ gsumsq) {
  int t = threadIdx.x, b = blockIdx.x;
  int i = b * 1024 + t;
  int lane = t & 63, wv = t >> 6;
  int v = (i < NL_NN) ? cnt[i] : 0;
  int sc = v;
#pragma unroll
  for (int off = 1; off < 64; off <<= 1) {
    int u = __shfl_up(sc, off);
    if (lane >= off) sc += u;
  }
  __shared__ int ws[16];
  if (lane == 63) ws[wv] = sc;
  __syncthreads();
  if (t < 16) {
    int xx = ws[t];
#pragma unroll
    for (int off = 1; off < 16; off <<= 1) {
      int u = __shfl_up(xx, off);
      if (t >= off) xx += u;
    }
    ws[t] = xx;
  }
  __syncthreads();
  int bofs = wv ? ws[wv - 1] : 0;
  if (i < NL_NN) scn[i] = bofs + sc - v;
  if (t == 0) btot[b] = ws[15];
  if (b == 200 && t < N_LAYERS * 32) {
    gsum[t] = 0.f;
    gsumsq[t] = 0.f;
  }
}

__global__ __launch_bounds__(512) void scan_b(const int* __restrict__ btot,
                                              int* __restrict__ boff) {
  int t = threadIdx.x;
  int lane = t & 63, wv = t >> 6;
  int v = (t < SCAN_BLKS) ? btot[t] : 0;
  int sc = v;
#pragma unroll
  for (int off = 1; off < 64; off <<= 1) {
    int u = __shfl_up(sc, off);
    if (lane >= off) sc += u;
  }
  __shared__ int ws[8];
  if (lane == 63) ws[wv] = sc;
  __syncthreads();
  if (t < 8) {
    int xx = ws[t];
#pragma unroll
    for (int off = 1; off < 8; off <<= 1) {
      int u = __shfl_up(xx, off);
      if (t >= off) xx += u;
    }
    ws[t] = xx;
  }
  __syncthreads();
  int bofs = wv ? ws[wv - 1] : 0;
  if (t < SCAN_BLKS) boff[t] = bofs + sc - v;
}

// ------- fill: edge-parallel, atomic-free; 32B records {w, x0..x4, 0, 0} ----
// tail builds CSR rowptr and zero-pads 4 records past TOTAL_E
__global__ __launch_bounds__(1024) void fill_kernel(const int* __restrict__ ei,
                                                    const float* __restrict__ ew,
                                                    const int* __restrict__ scn,
                                                    const int* __restrict__ boff,
                                                    const int* __restrict__ rank,
                                                    const float* __restrict__ xpad,
                                                    int* __restrict__ rowptr,
                                                    float* __restrict__ epf) {
  int b = blockIdx.x;
  if (b < EDGE_BLKS) {
    int idx = b * 1024 + threadIdx.x;
    if (idx >= TOTAL_E) return;
    int l = idx / N_EDGES, e = idx - l * N_EDGES;
    int src = ei[(size_t)l * 2 * N_EDGES + e];
    int dst = ei[(size_t)l * 2 * N_EDGES + N_EDGES + e];
    int g = l * N_NODES + dst;
    int pos = scn[g] + boff[g >> 10] + rank[idx];
    float w = ew[(size_t)l * N_EDGES + e];
    float4 xv = *(const float4*)(xpad + (size_t)src * 8);
    float x4v = xpad[(size_t)src * 8 + 4];
    float8v r;
    r[0] = w; r[1] = xv.x; r[2] = xv.y; r[3] = xv.z; r[4] = xv.w; r[5] = x4v;
    r[6] = 0.f; r[7] = 0.f;
    *(float8v*)(epf + (size_t)pos * 8) = r;
  } else {
    int i = (b - EDGE_BLKS) * 1024 + threadIdx.x;
    if (i < NL_NN) rowptr[i] = scn[i] + boff[i >> 10];
    if (i < 31) rowptr[NL_NN + i] = TOTAL_E;  // sentinel + OOB-read pad
    if (i < 4) {
      float8v z = {0.f, 0.f, 0.f, 0.f, 0.f, 0.f, 0.f, 0.f};
      *(float8v*)(epf + (size_t)(TOTAL_E + i) * 8) = z;
    }
  }
}

// ---------------- fused GAT layer: 1 wave per 8 (layer,node)s ----------------
// NPW=8 nodes/wave: CSR rowptr (9 offsets via one dual-dwordx8), layer params
// loaded once per wave, contiguous record stream. Cuts SMEM request count
// ~2.3x and wave count 8x vs 1-node-per-wave (SMEM-miss-concurrency theory).
__global__ __launch_bounds__(256) void attn_kernel(
    const float* __restrict__ xpad, const int* __restrict__ rowptr,
    const float* __restrict__ epf,
    const float* __restrict__ Wl, const float* __restrict__ bl,
    const float* __restrict__ Wr, const float* __restrict__ br,
    const float* __restrict__ We, const float* __restrict__ att,
    const float* __restrict__ cbias, unsigned short* __restrict__ out_pre) {
  int b = blockIdx.x;
  // m204 bijective XCD swizzle (ATTN_BLKS % 8 != 0)
  const int q = ATTN_BLKS >> 3, r = ATTN_BLKS & 7;
  int xcd = b & 7, ib = b >> 3;
  int nb = (xcd < r ? xcd * (q + 1) : r * (q + 1) + (xcd - r) * q) + ib;
  // wave-uniform by construction; readfirstlane makes it SGPR for the compiler
  int wid = __builtin_amdgcn_readfirstlane(nb * 4 + (threadIdx.x >> 6));
  int lane = threadIdx.x & 63;
  int l = wid / NPL;
  int n0 = (wid - l * NPL) * NPW;  // node id within graph, start of group

  // layer params, once per wave (L1/L2-hot)
  float wlv0 = Wl[(l * 5 + 0) * 64 + lane];
  float wlv1 = Wl[(l * 5 + 1) * 64 + lane];
  float wlv2 = Wl[(l * 5 + 2) * 64 + lane];
  float wlv3 = Wl[(l * 5 + 3) * 64 + lane];
  float wlv4 = Wl[(l * 5 + 4) * 64 + lane];
  float wr0 = Wr[(l * 5 + 0) * 64 + lane];
  float wr1 = Wr[(l * 5 + 1) * 64 + lane];
  float wr2 = Wr[(l * 5 + 2) * 64 + lane];
  float wr3 = Wr[(l * 5 + 3) * 64 + lane];
  float wr4 = Wr[(l * 5 + 4) * 64 + lane];
  float blv = bl[l * 64 + lane];
  float brv = br[l * 64 + lane];
  float wev = We[l * 64 + lane];
  float att2v = att[l * 64 + lane] * LOG2E;
  float cbv = cbias[l * 32 + (lane & 31)];

  // 9 CSR offsets for 8 nodes (rowptr global index = wid*8; 32B aligned)
  int8v rpa, rpb;
  sload_rp(rowptr + (size_t)wid * 8, rpa, rpb);

#pragma unroll
  for (int i = 0; i < NPW; i++) {
    int st = rpa[i & 7];
    int en = (i == 7) ? rpb[0] : rpa[(i + 1) & 7];
    int cnt = en - st;

    // own-node transforms from scalar x row
    int8v xn = sload8(xpad + (size_t)(n0 + i) * 8);
    float x0 = __int_as_float(xn[0]), x1 = __int_as_float(xn[1]);
    float x2 = __int_as_float(xn[2]), x3 = __int_as_float(xn[3]);
    float x4 = __int_as_float(xn[4]);
    float xrn = brv, xln = blv;
    xrn = fmaf(x0, wr0, xrn); xrn = fmaf(x1, wr1, xrn);
    xrn = fmaf(x2, wr2, xrn); xrn = fmaf(x3, wr3, xrn);
    xrn = fmaf(x4, wr4, xrn);
    xln = fmaf(x0, wlv0, xln); xln = fmaf(x1, wlv1, xln);
    xln = fmaf(x2, wlv2, xln); xln = fmaf(x3, wlv3, xln);
    xln = fmaf(x4, wlv4, xln);

    float ssum = 0.f, acc = 0.f, ewsum = 0.f;
    int nchunk = (cnt + 3) >> 2;
    const float* pch = epf + (size_t)st * 8;
    for (int c = 0; c < nchunk; c++) {
      int8v r0, r1, r2, r3;
      sload_chunk(pch, r0, r1, r2, r3);
      pch += 32;
      int m = cnt - c * 4;  // valid edges this chunk
      float xa[4], pk[4], wv[4];
#pragma unroll
      for (int k = 0; k < 4; k++) {
        int8v rr = (k == 0) ? r0 : (k == 1) ? r1 : (k == 2) ? r2 : r3;
        bool ok = k < m;                       // wave-uniform -> s_cselect
        int wbits = ok ? rr[0] : 0;
        wv[k] = __int_as_float(wbits);
        float a = fmaf(__int_as_float(rr[1]), wlv0, blv);
        a = fmaf(__int_as_float(rr[2]), wlv1, a);
        a = fmaf(__int_as_float(rr[3]), wlv2, a);
        a = fmaf(__int_as_float(rr[4]), wlv3, a);
        a = fmaf(__int_as_float(rr[5]), wlv4, a);
        xa[k] = a;
        float bias = __int_as_float(ok ? 0 : (int)0xff800000);  // -inf mask
        float v = a + fmaf(wv[k], wev, xrn);
        float lk = fmaxf(v, 0.2f * v);
        pk[k] = fmaf(lk, att2v, bias);
      }
      red4(pk[0], pk[1], pk[2], pk[3]);
#pragma unroll
      for (int k = 0; k < 4; k++) pk[k] += swz<0x401F>(pk[k]);
#pragma unroll
      for (int k = 0; k < 4; k++) {
        float pe = __builtin_amdgcn_exp2f(pk[k]);
        ssum += pe;
        acc = fmaf(xa[k], pe, acc);
        ewsum += wv[k];
      }
    }
    // self-loop edge with mean incoming weight
    {
      float w = ewsum * __builtin_amdgcn_rcpf(fmaxf((float)cnt, 1.f));
      float v = xln + fmaf(w, wev, xrn);
      float lk = fmaxf(v, 0.2f * v);
      float p = red1(lk * att2v);
      p += swz<0x401F>(p);
      float pe = __builtin_amdgcn_exp2f(p);
      ssum += pe;
      acc = fmaf(xln, pe, acc);
    }
    float outv = acc * __builtin_amdgcn_rcpf(ssum * (float)(cnt + 1));
    float o2 = outv + __shfl_xor(outv, 32);
    if (lane < 32)
      out_pre[((size_t)wid * NPW + i) * 32 + lane] = bfbits(0.5f * o2 + cbv);
  }
}

// ---------------- BatchNorm stats (bf16 input) ----------------
__global__ __launch_bounds__(256) void stats_kernel(const unsigned short* __restrict__ out_pre,
                                                    float* __restrict__ gsum,
                                                    float* __restrict__ gsumsq) {
  int l = blockIdx.x >> 4, chunk = blockIdx.x & 15;
  int t = threadIdx.x;
  int c = t & 31, nsub = t >> 5;
  int n0 = chunk * 1250;
  float s1 = 0.f, s2 = 0.f;
  for (int n = n0 + nsub; n < n0 + 1250; n += 8) {
    float v = ldbf(out_pre, (l * N_NODES + n) * 32 + c);
    s1 += v; s2 += v * v;
  }
  __shared__ float l1[256], l2[256];
  l1[t] = s1; l2[t] = s2;
  __syncthreads();
  for (int off = 128; off >= 32; off >>= 1) {
    if (t < off) { l1[t] += l1[t + off]; l2[t] += l2[t + off]; }
    __syncthreads();
  }
  if (t < 32) {
    atomicAdd(&gsum[l * 32 + t], l1[t]);
    atomicAdd(&gsumsq[l * 32 + t], l2[t]);
  }
}

// ---------------- normalize + leaky relu -> bf16 [L][NPAD][32] ----------------
__global__ __launch_bounds__(256) void norm_kernel(const unsigned short* __restrict__ out_pre,
                                                   const float* __restrict__ gsum,
                                                   const float* __restrict__ gsumsq,
                                                   const float* __restrict__ gamma,
                                                   const float* __restrict__ beta,
                                                   unsigned short* __restrict__ hn) {
  int idx = blockIdx.x * 256 + threadIdx.x;
  int l = idx / (N_NODES * 8);
  int rem = idx - l * (N_NODES * 8);
  int n = rem >> 3, q = rem & 7;
  int c0 = q * 4;
  short4v v4 = *(const short4v*)(out_pre + (l * N_NODES + n) * 32 + c0);
  short4v o;
#pragma unroll
  for (int i = 0; i < 4; i++) {
    int c = c0 + i;
    float mu = gsum[l * 32 + c] * (1.f / N_NODES);
    float var = gsumsq[l * 32 + c] * (1.f / N_NODES) - mu * mu;
    float vv = __uint_as_float((unsigned)(unsigned short)v4[i] << 16);
    float v = gamma[l * 32 + c] * (vv - mu) * rsqrtf(var + EPS_BN) + beta[l * 32 + c];
    v = v > 0.f ? v : 0.01f * v;
    o[i] = (short)bfbits(v);
  }
  *(short4v*)(hn + ((size_t)l * NPAD + n) * 32 + c0) = o;
}

// --- GEMM1: h @ W1 -> relu -> per-colgroup 5-dot partials (non-atomic) ------
// each (block, wc) writes disjoint p[row][group][5]; group = blockIdx.x*2+wc
__global__ __launch_bounds__(256) void gemm1_kernel(const short* __restrict__ hn,
                                                    const short* __restrict__ W1bT,
                                                    const float* __restrict__ b1,
                                                    const float* __restrict__ W2,
                                                    float* __restrict__ p) {
  __shared__ __align__(16) short As[128 * 32];
  __shared__ __align__(16) short Bs[128 * 32];
  int t = threadIdx.x;
  int n0 = blockIdx.x * 128, m0 = blockIdx.y * 128;
  int wave = t >> 6, lane = t & 63;
  int wr = wave >> 1, wc = wave & 1;
  int mrow = lane & 15, quad = lane >> 4;
  floatx4 acc[4][4];
#pragma unroll
  for (int i = 0; i < 4; i++)
#pragma unroll
    for (int j = 0; j < 4; j++) acc[i][j] = (floatx4){0.f, 0.f, 0.f, 0.f};

  int r0 = t >> 2, s0 = t & 3;
  int r1 = (t + 256) >> 2, s1 = (t + 256) & 3;
  const short* aG0 = hn + (m0 + r0) * 32 + s0 * 8;
  const short* aG1 = hn + (m0 + r1) * 32 + s1 * 8;
  const short* bG0 = W1bT + (n0 + r0) * 800 + s0 * 8;
  const short* bG1 = W1bT + (n0 + r1) * 800 + s1 * 8;
  const int ak = NPAD * 32;
  short* aD0 = As + wave * 512;
  short* aD1 = As + 2048 + wave * 512;
  short* bD0 = Bs + wave * 512;
  short* bD1 = Bs + 2048 + wave * 512;

  for (int kt = 0; kt < 25; kt++) {
    gl_lds16(aG0, aD0);
    gl_lds16(aG1, aD1);
    gl_lds16(bG0, bD0);
    gl_lds16(bG1, bD1);
    aG0 += ak; aG1 += ak; bG0 += 32; bG1 += 32;
    __syncthreads();
    short8 af[4], bfr[4];
#pragma unroll
    for (int i = 0; i < 4; i++)
      af[i] = *(const short8*)(&As[(wr * 64 + i * 16 + mrow) * 32 + quad * 8]);
#pragma unroll
    for (int j = 0; j < 4; j++)
      bfr[j] = *(const short8*)(&Bs[(wc * 64 + j * 16 + mrow) * 32 + quad * 8]);
#pragma unroll
    for (int i = 0; i < 4; i++)
#pragma unroll
      for (int j = 0; j < 4; j++)
        acc[i][j] = __builtin_amdgcn_mfma_f32_16x16x32_bf16(af[i], bfr[j], acc[i][j], 0, 0, 0);
    __syncthreads();
  }

  // epilogue: relu+bias, 5-dot with W2, 16-lane DPP reduce, disjoint stores
  float w2v[4][5];
  float b1v[4];
#pragma unroll
  for (int j = 0; j < 4; j++) {
    int col = n0 + wc * 64 + j * 16 + mrow;
    bool ok = col < 800;
    b1v[j] = ok ? b1[col] : 0.f;
#pragma unroll
    for (int jj = 0; jj < 5; jj++) w2v[j][jj] = ok ? W2[col * 5 + jj] : 0.f;
  }
  int grp = blockIdx.x * 2 + wc;
#pragma unroll
  for (int i = 0; i < 4; i++) {
#pragma unroll
    for (int r = 0; r < 4; r++) {
      float s[5] = {0.f, 0.f, 0.f, 0.f, 0.f};
#pragma unroll
      for (int j = 0; j < 4; j++) {
        float v = fmaxf(acc[i][j][r] + b1v[j], 0.f);
#pragma unroll
        for (int jj = 0; jj < 5; jj++) s[jj] = fmaf(v, w2v[j][jj], s[jj]);
      }
#pragma unroll
      for (int jj = 0; jj < 5; jj++) {
        s[jj] = dpp_add<0xB1>(s[jj]);
        s[jj] = dpp_add<0x4E>(s[jj]);
        s[jj] = dpp_add<0x141>(s[jj]);
        s[jj] = dpp_add<0x140>(s[jj]);
      }
      int row = m0 + wr * 64 + i * 16 + quad * 4 + r;
      if (mrow == 0) {
#pragma unroll
        for (int jj = 0; jj < 5; jj++)
          p[(row * NGRP + grp) * 5 + jj] = s[jj];
      }
    }
  }
}

// ---- gemm2r: out[row][jj] = b2[jj] + sum_g p[row][g][jj] -------------------
__global__ __launch_bounds__(256) void gemm2r_kernel(const float* __restrict__ p,
                                                     const float* __restrict__ b2,
                                                     float* __restrict__ out) {
  int idx = blockIdx.x * 256 + threadIdx.x;
  if (idx >= N_NODES * 5) return;
  int row = idx / 5, jj = idx - row * 5;
  float s = b2[jj];
#pragma unroll
  for (int g = 0; g < NGRP; g++) s += p[(row * NGRP + g) * 5 + jj];
  out[idx] = s;
}

extern "C" void kernel_launch(void* const* d_in, const int* in_sizes, int n_in,
                              void* d_out, int out_size, void* d_ws, size_t ws_size,
                              hipStream_t stream) {
  const float* x    = (const float*)d_in[0];
  const int*   ei   = (const int*)d_in[1];
  const float* ew   = (const float*)d_in[2];
  const float* Wl   = (const float*)d_in[3];
  const float* bl   = (const float*)d_in[4];
  const float* Wr   = (const float*)d_in[5];
  const float* br   = (const float*)d_in[6];
  const float* We   = (const float*)d_in[7];
  const float* att  = (const float*)d_in[8];
  const float* cb   = (const float*)d_in[9];
  const float* gam  = (const float*)d_in[10];
  const float* bet  = (const float*)d_in[11];
  const float* W1   = (const float*)d_in[12];
  const float* b1   = (const float*)d_in[13];
  const float* W2   = (const float*)d_in[14];
  const float* b2   = (const float*)d_in[15];

  char* ws = (char*)d_ws;
  size_t off = 0;
  auto alloc = [&](size_t bytes) {
    void* p = ws + off;
    off = (off + bytes + 255) & ~(size_t)255;
    return p;
  };
  int* cnt     = (int*)alloc((size_t)NL_NN * 4);
  int* scn     = (int*)alloc((size_t)NL_NN * 4);
  int* btot    = (int*)alloc(SCAN_BLKS * 4);
  int* boff    = (int*)alloc(SCAN_BLKS * 4);
  int* rank    = (int*)alloc((size_t)TOTAL_E * 4);
  int* rowptr  = (int*)alloc((size_t)(NL_NN + 32) * 4);
  float* epf   = (float*)alloc((size_t)TOTAL_E * 32 + 128);  // 32B recs + pad
  unsigned short* out_pre = (unsigned short*)alloc((size_t)NL_NN * 32 * 2);
  float* gsum   = (float*)alloc(N_LAYERS * 32 * 4);
  float* gsumsq = (float*)alloc(N_LAYERS * 32 * 4);
  float* xpad   = (float*)alloc((size_t)N_NODES * 8 * 4);
  __hip_bfloat16* w1t = (__hip_bfloat16*)alloc((size_t)896 * 800 * 2);
  float* pbuf = (float*)alloc((size_t)NPAD * NGRP * 5 * 4);  // 5.6 MB partials
  unsigned short* hn = (unsigned short*)alloc((size_t)N_LAYERS * NPAD * 32 * 2);

  prep_kernel<<<PREP_BLKS, 1024, 0, stream>>>(ei, x, W1, cnt, rank, xpad, w1t, hn);
  scan_a<<<SCAN_BLKS, 1024, 0, stream>>>(cnt, scn, btot, gsum, gsumsq);
  scan_b<<<1, 512, 0, stream>>>(btot, boff);
  fill_kernel<<<FILL_BLKS, 1024, 0, stream>>>(ei, ew, scn, boff, rank, xpad,
                                              rowptr, epf);
  attn_kernel<<<ATTN_BLKS, 256, 0, stream>>>(
      xpad, rowptr, epf, Wl, bl, Wr, br, We, att, cb, out_pre);
  stats_kernel<<<N_LAYERS * 16, 256, 0, stream>>>(out_pre, gsum, gsumsq);
  norm_kernel<<<(NL_NN * 8) / 256, 256, 0, stream>>>(
      out_pre, gsum, gsumsq, gam, bet, hn);
  gemm1_kernel<<<dim3(7, 157), 256, 0, stream>>>(
      (const short*)hn, (const short*)w1t, b1, W2, pbuf);
  gemm2r_kernel<<<(N_NODES * 5 + 255) / 256, 256, 0, stream>>>(
      pbuf, b2, (float*)d_out);
}

// Round 5
// 492.905 us; speedup vs baseline: 1.1285x; 1.0078x over previous
//
#include <hip/hip_runtime.h>
#include <hip/hip_bf16.h>

#define N_NODES 20000
#define N_EDGES 100000
#define N_LAYERS 25
#define NPAD 20096   // 157*128
#define EPS_BN 1e-5f
#define LOG2E 1.44269504088896340736f
#define NL_NN (N_LAYERS * N_NODES)          // 500000
#define TOTAL_E (N_LAYERS * N_EDGES)        // 2500000
#define SCAN_BLKS ((NL_NN + 1023) / 1024)   // 489
#define QUARTER_N 5000
#define CNT_BLKS (N_LAYERS * 4)             // 100
#define W1T_END (CNT_BLKS + 700)            // 800
#define XPAD_END (W1T_END + 157)            // 957
#define HPAD_BLKS 75                        // 25*96*32 shorts / 1024
#define PREP_BLKS (XPAD_END + HPAD_BLKS)    // 1032
#define EDGE_BLKS ((TOTAL_E + 1023) / 1024) // 2442
#define FILL_BLKS (EDGE_BLKS + SCAN_BLKS)
#define NGRP 14                             // 7 col-blocks x 2 wc halves
#define NPW 8                               // nodes per wave
#define NPL (N_NODES / NPW)                 // 2500 waves per layer
#define ATTN_WAVES (NL_NN / NPW)            // 62500
#define ATTN_BLKS (ATTN_WAVES / 4)          // 15625
#define CAP_E 512                           // staged edges per block (16 KB LDS)

typedef short short8 __attribute__((ext_vector_type(8)));
typedef short short4v __attribute__((ext_vector_type(4)));
typedef float floatx4 __attribute__((ext_vector_type(4)));
typedef float float8v __attribute__((ext_vector_type(8)));
typedef int int8v __attribute__((ext_vector_type(8)));
typedef int int2v __attribute__((ext_vector_type(2)));

template <int PAT>
__device__ __forceinline__ float swz(float v) {
  return __int_as_float(__builtin_amdgcn_ds_swizzle(__float_as_int(v), PAT));
}

template <int CTRL>
__device__ __forceinline__ float dpp_add(float v) {
  int r = __builtin_amdgcn_update_dpp(0, __float_as_int(v), CTRL, 0xF, 0xF, true);
  return v + __int_as_float(r);
}

// int index on purpose: 32-bit address math
__device__ __forceinline__ float ldbf(const unsigned short* __restrict__ p, int idx) {
  return __uint_as_float((unsigned)p[idx] << 16);
}

__device__ __forceinline__ unsigned short bfbits(float v) {
  return __builtin_bit_cast(unsigned short, (__hip_bfloat16)v);
}

// async global->LDS, 16B per lane; LDS dest = wave-uniform base + lane*16
__device__ __forceinline__ void gl_lds16(const short* g, short* l) {
  __builtin_amdgcn_global_load_lds(
      (const __attribute__((address_space(1))) void*)g,
      (__attribute__((address_space(3))) void*)l, 16, 0, 0);
}

// scalar load of one 32B record + wait (single asm: wait inseparable)
__device__ __forceinline__ int8v sload8(const void* p) {
  int8v r;
  asm volatile(
      "s_load_dwordx8 %0, %1, 0x0\n\t"
      "s_waitcnt lgkmcnt(0)"
      : "=s"(r)
      : "s"(p));
  return r;
}

// scalar load of 16 ints (two dwordx8, 32B-aligned) + wait
__device__ __forceinline__ void sload_rp(const void* p, int8v& a, int8v& b) {
  asm volatile(
      "s_load_dwordx8 %0, %2, 0x0\n\t"
      "s_load_dwordx8 %1, %2, 0x20\n\t"
      "s_waitcnt lgkmcnt(0)"
      : "=s"(a), "=s"(b)
      : "s"(p));
}

// scalar load of a 4-record chunk (128B) in one block; single wait
__device__ __forceinline__ void sload_chunk(const void* p, int8v& r0, int8v& r1,
                                            int8v& r2, int8v& r3) {
  asm volatile(
      "s_load_dwordx8 %0, %4, 0x0\n\t"
      "s_load_dwordx8 %1, %4, 0x20\n\t"
      "s_load_dwordx8 %2, %4, 0x40\n\t"
      "s_load_dwordx8 %3, %4, 0x60\n\t"
      "s_waitcnt lgkmcnt(0)"
      : "=s"(r0), "=s"(r1), "=s"(r2), "=s"(r3)
      : "s"(p));
}

// 4-chain interleaved 16-lane reduce: single-instruction DPP adds.
// 4-way interleave gives 3-instr gaps (>=2 wait states VALU->DPP);
// s_nop 1 guards asm entry/exit adjacency.
__device__ __forceinline__ void red4(float& p0, float& p1, float& p2, float& p3) {
  asm volatile(
      "s_nop 1\n\t"
      "v_add_f32_dpp %0, %0, %0 quad_perm:[1,0,3,2] row_mask:0xf bank_mask:0xf\n\t"
      "v_add_f32_dpp %1, %1, %1 quad_perm:[1,0,3,2] row_mask:0xf bank_mask:0xf\n\t"
      "v_add_f32_dpp %2, %2, %2 quad_perm:[1,0,3,2] row_mask:0xf bank_mask:0xf\n\t"
      "v_add_f32_dpp %3, %3, %3 quad_perm:[1,0,3,2] row_mask:0xf bank_mask:0xf\n\t"
      "v_add_f32_dpp %0, %0, %0 quad_perm:[2,3,0,1] row_mask:0xf bank_mask:0xf\n\t"
      "v_add_f32_dpp %1, %1, %1 quad_perm:[2,3,0,1] row_mask:0xf bank_mask:0xf\n\t"
      "v_add_f32_dpp %2, %2, %2 quad_perm:[2,3,0,1] row_mask:0xf bank_mask:0xf\n\t"
      "v_add_f32_dpp %3, %3, %3 quad_perm:[2,3,0,1] row_mask:0xf bank_mask:0xf\n\t"
      "v_add_f32_dpp %0, %0, %0 row_half_mirror row_mask:0xf bank_mask:0xf\n\t"
      "v_add_f32_dpp %1, %1, %1 row_half_mirror row_mask:0xf bank_mask:0xf\n\t"
      "v_add_f32_dpp %2, %2, %2 row_half_mirror row_mask:0xf bank_mask:0xf\n\t"
      "v_add_f32_dpp %3, %3, %3 row_half_mirror row_mask:0xf bank_mask:0xf\n\t"
      "v_add_f32_dpp %0, %0, %0 row_mirror row_mask:0xf bank_mask:0xf\n\t"
      "v_add_f32_dpp %1, %1, %1 row_mirror row_mask:0xf bank_mask:0xf\n\t"
      "v_add_f32_dpp %2, %2, %2 row_mirror row_mask:0xf bank_mask:0xf\n\t"
      "v_add_f32_dpp %3, %3, %3 row_mirror row_mask:0xf bank_mask:0xf\n\t"
      "s_nop 1"
      : "+v"(p0), "+v"(p1), "+v"(p2), "+v"(p3));
}

// single-chain 16-lane reduce (self-loop), s_nop 1 padding for DPP hazards
__device__ __forceinline__ float red1(float p) {
  asm volatile(
      "s_nop 1\n\t"
      "v_add_f32_dpp %0, %0, %0 quad_perm:[1,0,3,2] row_mask:0xf bank_mask:0xf\n\t"
      "s_nop 1\n\t"
      "v_add_f32_dpp %0, %0, %0 quad_perm:[2,3,0,1] row_mask:0xf bank_mask:0xf\n\t"
      "s_nop 1\n\t"
      "v_add_f32_dpp %0, %0, %0 row_half_mirror row_mask:0xf bank_mask:0xf\n\t"
      "s_nop 1\n\t"
      "v_add_f32_dpp %0, %0, %0 row_mirror row_mask:0xf bank_mask:0xf\n\t"
      "s_nop 1"
      : "+v"(p));
  return p;
}

// --- prep: count hist (rank capture) + W1^T + xpad copy + hn pad zero -------
__global__ __launch_bounds__(1024) void prep_kernel(
    const int* __restrict__ ei, const float* __restrict__ x,
    const float* __restrict__ W1, int* __restrict__ cnt,
    int* __restrict__ rank, float* __restrict__ xpad,
    __hip_bfloat16* __restrict__ W1bT, unsigned short* __restrict__ hn) {
  __shared__ int smem[QUARTER_N];  // 20 KB (count hist); w1t reuses as float tile
  int b = blockIdx.x;
  if (b < CNT_BLKS) {
    int l = b >> 2, base = (b & 3) * QUARTER_N;
    for (int i = threadIdx.x; i < QUARTER_N; i += 1024) smem[i] = 0;
    __syncthreads();
    const int* dstp = ei + (size_t)l * 2 * N_EDGES + N_EDGES;
    int* rkp = rank + l * N_EDGES;
    for (int e = threadIdx.x; e < N_EDGES; e += 1024) {
      int d = dstp[e] - base;
      if ((unsigned)d < (unsigned)QUARTER_N) rkp[e] = atomicAdd(&smem[d], 1);
    }
    __syncthreads();
    int* outp = cnt + l * N_NODES + base;
    for (int i = threadIdx.x; i < QUARTER_N; i += 1024) outp[i] = smem[i];
  } else if (b < W1T_END) {
    float* tile = (float*)smem;  // [32][33]
    int bb = b - CNT_BLKS;
    int j0 = (bb % 28) * 32, k0 = (bb / 28) * 32;
    int tx = threadIdx.x & 31, ty = threadIdx.x >> 5;
    tile[ty * 33 + tx] = (j0 + tx < 800) ? W1[(k0 + ty) * 800 + j0 + tx] : 0.f;
    __syncthreads();
    W1bT[(size_t)(j0 + ty) * 800 + k0 + tx] = (__hip_bfloat16)tile[tx * 33 + ty];
  } else if (b < XPAD_END) {
    int idx = (b - W1T_END) * 1024 + threadIdx.x;
    if (idx < N_NODES * 8) {
      int nn = idx >> 3, k = idx & 7;
      xpad[idx] = (k < 5) ? x[nn * 5 + k] : 0.f;
    }
  } else {
    // zero hn pad rows (N_NODES..NPAD) so gemm1 reads finite values
    int idx = (b - XPAD_END) * 1024 + threadIdx.x;
    const int per_l = (NPAD - N_NODES) * 32;  // 3072
    if (idx < N_LAYERS * per_l) {
      int l = idx / per_l;
      int rem = idx - l * per_l;
      hn[((size_t)l * NPAD + N_NODES) * 32 + rem] = 0;
    }
  }
}

// -------- scan_a: per-block scan; also zero gsum/gsumsq ---------------------
__global__ __launch_bounds__(1024) void scan_a(const int* __restrict__ cnt,
                                               int* __restrict__ scn,
                                               int* __restrict__ btot,
                                               float* __restrict__ gsum,
                                               float* __restrict__ gsumsq) {
  int t = threadIdx.x, b = blockIdx.x;
  int i = b * 1024 + t;
  int lane = t & 63, wv = t >> 6;
  int v = (i < NL_NN) ? cnt[i] : 0;
  int sc = v;
#pragma unroll
  for (int off = 1; off < 64; off <<= 1) {
    int u = __shfl_up(sc, off);
    if (lane >= off) sc += u;
  }
  __shared__ int ws[16];
  if (lane == 63) ws[wv] = sc;
  __syncthreads();
  if (t < 16) {
    int xx = ws[t];
#pragma unroll
    for (int off = 1; off < 16; off <<= 1) {
      int u = __shfl_up(xx, off);
      if (t >= off) xx += u;
    }
    ws[t] = xx;
  }
  __syncthreads();
  int bofs = wv ? ws[wv - 1] : 0;
  if (i < NL_NN) scn[i] = bofs + sc - v;
  if (t == 0) btot[b] = ws[15];
  if (b == 200 && t < N_LAYERS * 32) {
    gsum[t] = 0.f;
    gsumsq[t] = 0.f;
  }
}

__global__ __launch_bounds__(512) void scan_b(const int* __restrict__ btot,
                                              int* __restrict__ boff) {
  int t = threadIdx.x;
  int lane = t & 63, wv = t >> 6;
  int v = (t < SCAN_BLKS) ? btot[t] : 0;
  int sc = v;
#pragma unroll
  for (int off = 1; off < 64; off <<= 1) {
    int u = __shfl_up(sc, off);
    if (lane >= off) sc += u;
  }
  __shared__ int ws[8];
  if (lane == 63) ws[wv] = sc;
  __syncthreads();
  if (t < 8) {
    int xx = ws[t];
#pragma unroll
    for (int off = 1; off < 8; off <<= 1) {
      int u = __shfl_up(xx, off);
      if (t >= off) xx += u;
    }
    ws[t] = xx;
  }
  __syncthreads();
  int bofs = wv ? ws[wv - 1] : 0;
  if (t < SCAN_BLKS) boff[t] = bofs + sc - v;
}

// ------- fill: edge-parallel, atomic-free; 32B records {w, x0..x4, 0, 0} ----
// tail builds CSR rowptr and zero-pads 4 records past TOTAL_E
__global__ __launch_bounds__(1024) void fill_kernel(const int* __restrict__ ei,
                                                    const float* __restrict__ ew,
                                                    const int* __restrict__ scn,
                                                    const int* __restrict__ boff,
                                                    const int* __restrict__ rank,
                                                    const float* __restrict__ xpad,
                                                    int* __restrict__ rowptr,
                                                    float* __restrict__ epf) {
  int b = blockIdx.x;
  if (b < EDGE_BLKS) {
    int idx = b * 1024 + threadIdx.x;
    if (idx >= TOTAL_E) return;
    int l = idx / N_EDGES, e = idx - l * N_EDGES;
    int src = ei[(size_t)l * 2 * N_EDGES + e];
    int dst = ei[(size_t)l * 2 * N_EDGES + N_EDGES + e];
    int g = l * N_NODES + dst;
    int pos = scn[g] + boff[g >> 10] + rank[idx];
    float w = ew[(size_t)l * N_EDGES + e];
    float4 xv = *(const float4*)(xpad + (size_t)src * 8);
    float x4v = xpad[(size_t)src * 8 + 4];
    float8v r;
    r[0] = w; r[1] = xv.x; r[2] = xv.y; r[3] = xv.z; r[4] = xv.w; r[5] = x4v;
    r[6] = 0.f; r[7] = 0.f;
    *(float8v*)(epf + (size_t)pos * 8) = r;
  } else {
    int i = (b - EDGE_BLKS) * 1024 + threadIdx.x;
    if (i < NL_NN) rowptr[i] = scn[i] + boff[i >> 10];
    if (i < 31) rowptr[NL_NN + i] = TOTAL_E;  // sentinel + OOB-read pad
    if (i < 4) {
      float8v z = {0.f, 0.f, 0.f, 0.f, 0.f, 0.f, 0.f, 0.f};
      *(float8v*)(epf + (size_t)(TOTAL_E + i) * 8) = z;
    }
  }
}

// ---------------- fused GAT layer: 4 waves x 8 nodes per block --------------
// Edge-record stream staged HBM->LDS per block via global_load_lds (vmcnt,
// in-order, deeply pipelined: ONE amortized round trip per block), then read
// with uniform-address ds_read_b128 (HW broadcast). Inner loop is DS-only;
// SMEM only in prologue + rare capacity-overflow fallback. This removes the
// serial, non-pipelinable SMEM latency chain that bounded rounds 2-4.
__global__ __launch_bounds__(256) void attn_kernel(
    const float* __restrict__ xpad, const int* __restrict__ rowptr,
    const float* __restrict__ epf,
    const float* __restrict__ Wl, const float* __restrict__ bl,
    const float* __restrict__ Wr, const float* __restrict__ br,
    const float* __restrict__ We, const float* __restrict__ att,
    const float* __restrict__ cbias, unsigned short* __restrict__ out_pre) {
  __shared__ __align__(16) float ldse[CAP_E * 8];  // 16 KB record cache
  int b = blockIdx.x;
  // m204 bijective XCD swizzle (ATTN_BLKS % 8 != 0)
  const int q = ATTN_BLKS >> 3, r = ATTN_BLKS & 7;
  int xcd = b & 7, ib = b >> 3;
  int nb = (xcd < r ? xcd * (q + 1) : r * (q + 1) + (xcd - r) * q) + ib;
  int tid = threadIdx.x;
  int w = tid >> 6, lane = tid & 63;
  int wid0 = nb * 4;
  int wid = __builtin_amdgcn_readfirstlane(wid0 + w);

  // ---- block-level staging of the contiguous record range ----
  int bs = __builtin_amdgcn_readfirstlane(rowptr[wid0 * 8]);
  int be = __builtin_amdgcn_readfirstlane(rowptr[wid0 * 8 + 32]);
  int want = be - bs + 4;  // +4: cover partial-chunk overshoot of last node
  int staged = want < CAP_E ? want : CAP_E;
  int rounds = (staged * 32 + 4095) >> 12;  // 4KB per round (256 lanes x 16B)
  const char* srcb = (const char*)epf + (size_t)bs * 32;
  for (int rr2 = 0; rr2 < rounds; rr2++) {
    int blk16 = (rr2 * 4 + w) * 64;  // wave-uniform 16B-chunk base
    gl_lds16((const short*)(srcb + (size_t)(blk16 + lane) * 16),
             (short*)((char*)ldse + (size_t)blk16 * 16));
  }

  int l = wid / NPL;
  int n0 = (wid - l * NPL) * NPW;

  // layer params, once per wave (L1/L2-hot)
  float wlv0 = Wl[(l * 5 + 0) * 64 + lane];
  float wlv1 = Wl[(l * 5 + 1) * 64 + lane];
  float wlv2 = Wl[(l * 5 + 2) * 64 + lane];
  float wlv3 = Wl[(l * 5 + 3) * 64 + lane];
  float wlv4 = Wl[(l * 5 + 4) * 64 + lane];
  float wr0 = Wr[(l * 5 + 0) * 64 + lane];
  float wr1 = Wr[(l * 5 + 1) * 64 + lane];
  float wr2 = Wr[(l * 5 + 2) * 64 + lane];
  float wr3 = Wr[(l * 5 + 3) * 64 + lane];
  float wr4 = Wr[(l * 5 + 4) * 64 + lane];
  float blv = bl[l * 64 + lane];
  float brv = br[l * 64 + lane];
  float wev = We[l * 64 + lane];
  float att2v = att[l * 64 + lane] * LOG2E;
  float cbv = cbias[l * 32 + (lane & 31)];

  // 9 CSR offsets for this wave's 8 nodes
  int8v rpa, rpb;
  sload_rp(rowptr + (size_t)wid * 8, rpa, rpb);

  __syncthreads();  // drains vmcnt(0): staged records visible

#pragma unroll
  for (int i = 0; i < NPW; i++) {
    int st = rpa[i & 7];
    int en = (i == 7) ? rpb[0] : rpa[(i + 1) & 7];
    int cnt = en - st;

    // own-node transforms from scalar x row
    int8v xn = sload8(xpad + (size_t)(n0 + i) * 8);
    float x0 = __int_as_float(xn[0]), x1 = __int_as_float(xn[1]);
    float x2 = __int_as_float(xn[2]), x3 = __int_as_float(xn[3]);
    float x4 = __int_as_float(xn[4]);
    float xrn = brv, xln = blv;
    xrn = fmaf(x0, wr0, xrn); xrn = fmaf(x1, wr1, xrn);
    xrn = fmaf(x2, wr2, xrn); xrn = fmaf(x3, wr3, xrn);
    xrn = fmaf(x4, wr4, xrn);
    xln = fmaf(x0, wlv0, xln); xln = fmaf(x1, wlv1, xln);
    xln = fmaf(x2, wlv2, xln); xln = fmaf(x3, wlv3, xln);
    xln = fmaf(x4, wlv4, xln);

    float ssum = 0.f, acc = 0.f, ewsum = 0.f;
    int nchunk = (cnt + 3) >> 2;
    for (int c = 0; c < nchunk; c++) {
      int m = cnt - c * 4;       // valid edges this chunk
      int g = st + c * 4;        // global record index (scalar)
      float aw[4], av[4][5];
      if (g - bs + 4 <= staged) {
        // LDS broadcast path: uniform-address ds_read_b128 pairs
        int co = (g - bs) * 32;
#pragma unroll
        for (int k = 0; k < 4; k++) {
          float4 p0 = *(const float4*)((const char*)ldse + (co + k * 32));
          float4 p1 = *(const float4*)((const char*)ldse + (co + k * 32 + 16));
          aw[k] = p0.x;
          av[k][0] = p0.y; av[k][1] = p0.z; av[k][2] = p0.w;
          av[k][3] = p1.x; av[k][4] = p1.y;
        }
      } else {
        // rare overflow fallback: scalar chunk load
        int8v r0, r1, r2, r3;
        sload_chunk(epf + (size_t)g * 8, r0, r1, r2, r3);
#pragma unroll
        for (int k = 0; k < 4; k++) {
          int8v rrv = (k == 0) ? r0 : (k == 1) ? r1 : (k == 2) ? r2 : r3;
          aw[k] = __int_as_float(rrv[0]);
#pragma unroll
          for (int j = 0; j < 5; j++) av[k][j] = __int_as_float(rrv[1 + j]);
        }
      }
      float xa[4], pk[4], wv[4];
#pragma unroll
      for (int k = 0; k < 4; k++) {
        bool ok = k < m;  // wave-uniform
        wv[k] = ok ? aw[k] : 0.f;
        float a = fmaf(av[k][0], wlv0, blv);
        a = fmaf(av[k][1], wlv1, a);
        a = fmaf(av[k][2], wlv2, a);
        a = fmaf(av[k][3], wlv3, a);
        a = fmaf(av[k][4], wlv4, a);
        xa[k] = a;
        float bias = __int_as_float(ok ? 0 : (int)0xff800000);  // -inf mask
        float v = a + fmaf(wv[k], wev, xrn);
        float lk = fmaxf(v, 0.2f * v);
        pk[k] = fmaf(lk, att2v, bias);
      }
      red4(pk[0], pk[1], pk[2], pk[3]);
#pragma unroll
      for (int k = 0; k < 4; k++) pk[k] += swz<0x401F>(pk[k]);
#pragma unroll
      for (int k = 0; k < 4; k++) {
        float pe = __builtin_amdgcn_exp2f(pk[k]);
        ssum += pe;
        acc = fmaf(xa[k], pe, acc);
        ewsum += wv[k];
      }
    }
    // self-loop edge with mean incoming weight
    {
      float wsl = ewsum * __builtin_amdgcn_rcpf(fmaxf((float)cnt, 1.f));
      float v = xln + fmaf(wsl, wev, xrn);
      float lk = fmaxf(v, 0.2f * v);
      float p = red1(lk * att2v);
      p += swz<0x401F>(p);
      float pe = __builtin_amdgcn_exp2f(p);
      ssum += pe;
      acc = fmaf(xln, pe, acc);
    }
    float outv = acc * __builtin_amdgcn_rcpf(ssum * (float)(cnt + 1));
    float o2 = outv + __shfl_xor(outv, 32);
    if (lane < 32)
      out_pre[((size_t)wid * NPW + i) * 32 + lane] = bfbits(0.5f * o2 + cbv);
  }
}

// ---------------- BatchNorm stats (bf16 input) ----------------
__global__ __launch_bounds__(256) void stats_kernel(const unsigned short* __restrict__ out_pre,
                                                    float* __restrict__ gsum,
                                                    float* __restrict__ gsumsq) {
  int l = blockIdx.x >> 4, chunk = blockIdx.x & 15;
  int t = threadIdx.x;
  int c = t & 31, nsub = t >> 5;
  int n0 = chunk * 1250;
  float s1 = 0.f, s2 = 0.f;
  for (int n = n0 + nsub; n < n0 + 1250; n += 8) {
    float v = ldbf(out_pre, (l * N_NODES + n) * 32 + c);
    s1 += v; s2 += v * v;
  }
  __shared__ float l1[256], l2[256];
  l1[t] = s1; l2[t] = s2;
  __syncthreads();
  for (int off = 128; off >= 32; off >>= 1) {
    if (t < off) { l1[t] += l1[t + off]; l2[t] += l2[t + off]; }
    __syncthreads();
  }
  if (t < 32) {
    atomicAdd(&gsum[l * 32 + t], l1[t]);
    atomicAdd(&gsumsq[l * 32 + t], l2[t]);
  }
}

// ---------------- normalize + leaky relu -> bf16 [L][NPAD][32] ----------------
__global__ __launch_bounds__(256) void norm_kernel(const unsigned short* __restrict__ out_pre,
                                                   const float* __restrict__ gsum,
                                                   const float* __restrict__ gsumsq,
                                                   const float* __restrict__ gamma,
                                                   const float* __restrict__ beta,
                                                   unsigned short* __restrict__ hn) {
  int idx = blockIdx.x * 256 + threadIdx.x;
  int l = idx / (N_NODES * 8);
  int rem = idx - l * (N_NODES * 8);
  int n = rem >> 3, q = rem & 7;
  int c0 = q * 4;
  short4v v4 = *(const short4v*)(out_pre + (l * N_NODES + n) * 32 + c0);
  short4v o;
#pragma unroll
  for (int i = 0; i < 4; i++) {
    int c = c0 + i;
    float mu = gsum[l * 32 + c] * (1.f / N_NODES);
    float var = gsumsq[l * 32 + c] * (1.f / N_NODES) - mu * mu;
    float vv = __uint_as_float((unsigned)(unsigned short)v4[i] << 16);
    float v = gamma[l * 32 + c] * (vv - mu) * rsqrtf(var + EPS_BN) + beta[l * 32 + c];
    v = v > 0.f ? v : 0.01f * v;
    o[i] = (short)bfbits(v);
  }
  *(short4v*)(hn + ((size_t)l * NPAD + n) * 32 + c0) = o;
}

// --- GEMM1: h @ W1 -> relu -> per-colgroup 5-dot partials (non-atomic) ------
// each (block, wc) writes disjoint p[row][group][5]; group = blockIdx.x*2+wc
__global__ __launch_bounds__(256) void gemm1_kernel(const short* __restrict__ hn,
                                                    const short* __restrict__ W1bT,
                                                    const float* __restrict__ b1,
                                                    const float* __restrict__ W2,
                                                    float* __restrict__ p) {
  __shared__ __align__(16) short As[128 * 32];
  __shared__ __align__(16) short Bs[128 * 32];
  int t = threadIdx.x;
  int n0 = blockIdx.x * 128, m0 = blockIdx.y * 128;
  int wave = t >> 6, lane = t & 63;
  int wr = wave >> 1, wc = wave & 1;
  int mrow = lane & 15, quad = lane >> 4;
  floatx4 acc[4][4];
#pragma unroll
  for (int i = 0; i < 4; i++)
#pragma unroll
    for (int j = 0; j < 4; j++) acc[i][j] = (floatx4){0.f, 0.f, 0.f, 0.f};

  int r0 = t >> 2, s0 = t & 3;
  int r1 = (t + 256) >> 2, s1 = (t + 256) & 3;
  const short* aG0 = hn + (m0 + r0) * 32 + s0 * 8;
  const short* aG1 = hn + (m0 + r1) * 32 + s1 * 8;
  const short* bG0 = W1bT + (n0 + r0) * 800 + s0 * 8;
  const short* bG1 = W1bT + (n0 + r1) * 800 + s1 * 8;
  const int ak = NPAD * 32;
  short* aD0 = As + wave * 512;
  short* aD1 = As + 2048 + wave * 512;
  short* bD0 = Bs + wave * 512;
  short* bD1 = Bs + 2048 + wave * 512;

  for (int kt = 0; kt < 25; kt++) {
    gl_lds16(aG0, aD0);
    gl_lds16(aG1, aD1);
    gl_lds16(bG0, bD0);
    gl_lds16(bG1, bD1);
    aG0 += ak; aG1 += ak; bG0 += 32; bG1 += 32;
    __syncthreads();
    short8 af[4], bfr[4];
#pragma unroll
    for (int i = 0; i < 4; i++)
      af[i] = *(const short8*)(&As[(wr * 64 + i * 16 + mrow) * 32 + quad * 8]);
#pragma unroll
    for (int j = 0; j < 4; j++)
      bfr[j] = *(const short8*)(&Bs[(wc * 64 + j * 16 + mrow) * 32 + quad * 8]);
#pragma unroll
    for (int i = 0; i < 4; i++)
#pragma unroll
      for (int j = 0; j < 4; j++)
        acc[i][j] = __builtin_amdgcn_mfma_f32_16x16x32_bf16(af[i], bfr[j], acc[i][j], 0, 0, 0);
    __syncthreads();
  }

  // epilogue: relu+bias, 5-dot with W2, 16-lane DPP reduce, disjoint stores
  float w2v[4][5];
  float b1v[4];
#pragma unroll
  for (int j = 0; j < 4; j++) {
    int col = n0 + wc * 64 + j * 16 + mrow;
    bool ok = col < 800;
    b1v[j] = ok ? b1[col] : 0.f;
#pragma unroll
    for (int jj = 0; jj < 5; jj++) w2v[j][jj] = ok ? W2[col * 5 + jj] : 0.f;
  }
  int grp = blockIdx.x * 2 + wc;
#pragma unroll
  for (int i = 0; i < 4; i++) {
#pragma unroll
    for (int r = 0; r < 4; r++) {
      float s[5] = {0.f, 0.f, 0.f, 0.f, 0.f};
#pragma unroll
      for (int j = 0; j < 4; j++) {
        float v = fmaxf(acc[i][j][r] + b1v[j], 0.f);
#pragma unroll
        for (int jj = 0; jj < 5; jj++) s[jj] = fmaf(v, w2v[j][jj], s[jj]);
      }
#pragma unroll
      for (int jj = 0; jj < 5; jj++) {
        s[jj] = dpp_add<0xB1>(s[jj]);
        s[jj] = dpp_add<0x4E>(s[jj]);
        s[jj] = dpp_add<0x141>(s[jj]);
        s[jj] = dpp_add<0x140>(s[jj]);
      }
      int row = m0 + wr * 64 + i * 16 + quad * 4 + r;
      if (mrow == 0) {
#pragma unroll
        for (int jj = 0; jj < 5; jj++)
          p[(row * NGRP + grp) * 5 + jj] = s[jj];
      }
    }
  }
}

// ---- gemm2r: out[row][jj] = b2[jj] + sum_g p[row][g][jj] -------------------
__global__ __launch_bounds__(256) void gemm2r_kernel(const float* __restrict__ p,
                                                     const float* __restrict__ b2,
                                                     float* __restrict__ out) {
  int idx = blockIdx.x * 256 + threadIdx.x;
  if (idx >= N_NODES * 5) return;
  int row = idx / 5, jj = idx - row * 5;
  float s = b2[jj];
#pragma unroll
  for (int g = 0; g < NGRP; g++) s += p[(row * NGRP + g) * 5 + jj];
  out[idx] = s;
}

extern "C" void kernel_launch(void* const* d_in, const int* in_sizes, int n_in,
                              void* d_out, int out_size, void* d_ws, size_t ws_size,
                              hipStream_t stream) {
  const float* x    = (const float*)d_in[0];
  const int*   ei   = (const int*)d_in[1];
  const float* ew   = (const float*)d_in[2];
  const float* Wl   = (const float*)d_in[3];
  const float* bl   = (const float*)d_in[4];
  const float* Wr   = (const float*)d_in[5];
  const float* br   = (const float*)d_in[6];
  const float* We   = (const float*)d_in[7];
  const float* att  = (const float*)d_in[8];
  const float* cb   = (const float*)d_in[9];
  const float* gam  = (const float*)d_in[10];
  const float* bet  = (const float*)d_in[11];
  const float* W1   = (const float*)d_in[12];
  const float* b1   = (const float*)d_in[13];
  const float* W2   = (const float*)d_in[14];
  const float* b2   = (const float*)d_in[15];

  char* ws = (char*)d_ws;
  size_t off = 0;
  auto alloc = [&](size_t bytes) {
    void* p = ws + off;
    off = (off + bytes + 255) & ~(size_t)255;
    return p;
  };
  int* cnt     = (int*)alloc((size_t)NL_NN * 4);
  int* scn     = (int*)alloc((size_t)NL_NN * 4);
  int* btot    = (int*)alloc(SCAN_BLKS * 4);
  int* boff    = (int*)alloc(SCAN_BLKS * 4);
  int* rank    = (int*)alloc((size_t)TOTAL_E * 4);
  int* rowptr  = (int*)alloc((size_t)(NL_NN + 32) * 4);
  float* epf   = (float*)alloc((size_t)TOTAL_E * 32 + 32768);  // 32B recs + staging pad
  unsigned short* out_pre = (unsigned short*)alloc((size_t)NL_NN * 32 * 2);
  float* gsum   = (float*)alloc(N_LAYERS * 32 * 4);
  float* gsumsq = (float*)alloc(N_LAYERS * 32 * 4);
  float* xpad   = (float*)alloc((size_t)N_NODES * 8 * 4);
  __hip_bfloat16* w1t = (__hip_bfloat16*)alloc((size_t)896 * 800 * 2);
  float* pbuf = (float*)alloc((size_t)NPAD * NGRP * 5 * 4);  // 5.6 MB partials
  unsigned short* hn = (unsigned short*)alloc((size_t)N_LAYERS * NPAD * 32 * 2);

  prep_kernel<<<PREP_BLKS, 1024, 0, stream>>>(ei, x, W1, cnt, rank, xpad, w1t, hn);
  scan_a<<<SCAN_BLKS, 1024, 0, stream>>>(cnt, scn, btot, gsum, gsumsq);
  scan_b<<<1, 512, 0, stream>>>(btot, boff);
  fill_kernel<<<FILL_BLKS, 1024, 0, stream>>>(ei, ew, scn, boff, rank, xpad,
                                              rowptr, epf);
  attn_kernel<<<ATTN_BLKS, 256, 0, stream>>>(
      xpad, rowptr, epf, Wl, bl, Wr, br, We, att, cb, out_pre);
  stats_kernel<<<N_LAYERS * 16, 256, 0, stream>>>(out_pre, gsum, gsumsq);
  norm_kernel<<<(NL_NN * 8) / 256, 256, 0, stream>>>(
      out_pre, gsum, gsumsq, gam, bet, hn);
  gemm1_kernel<<<dim3(7, 157), 256, 0, stream>>>(
      (const short*)hn, (const short*)w1t, b1, W2, pbuf);
  gemm2r_kernel<<<(N_NODES * 5 + 255) / 256, 256, 0, stream>>>(
      pbuf, b2, (float*)d_out);
}